// Round 16
// baseline (327.506 us; speedup 1.0000x reference)
//
#include <hip/hip_runtime.h>
#include <hip/hip_cooperative_groups.h>

namespace cg = cooperative_groups;

// ResNeXt sparse-voxel block, MI355X. Round 16: cooperative fused kernel,
// fixed for launchability (r15 lesson: 78.5KB static LDS + unchecked coop
// launch = silent no-op). Conv phase TJ=256 -> LDS union ~44KB (<64KB, and
// 3 blocks/CU co-residency headroom for the 512-block coop grid; each block
// runs 2 (p,T) pairs). Launch return code checked; on ANY error the proven
// r14 5-kernel pipeline (same TJ=256 layout) is enqueued instead.

#define NN    65536
#define CIN   128
#define CPATH 32
#define NPATH 4
#define NK    27
#define TJ    256
#define NTILE (NN / TJ)    // 256
#define MAXG  192
#define SCALE_F 2097152.0f          // 2^21
#define INV_SCALE 4.76837158203125e-7f

typedef __attribute__((ext_vector_type(8))) short bfx8;
typedef __attribute__((ext_vector_type(4))) float fx4;

__device__ __forceinline__ unsigned short f2bf(float f) {
    unsigned u = __builtin_bit_cast(unsigned, f);
    u += 0x7FFFu + ((u >> 16) & 1u);
    return (unsigned short)(u >> 16);
}
__device__ __forceinline__ float bf2f(unsigned short s) {
    return __builtin_bit_cast(float, (unsigned)s << 16);
}
__device__ __forceinline__ bfx8 pack_bf8(const float4 a, const float4 b) {
    union { unsigned short s[8]; bfx8 v; } u;
    u.s[0] = f2bf(a.x); u.s[1] = f2bf(a.y); u.s[2] = f2bf(a.z); u.s[3] = f2bf(a.w);
    u.s[4] = f2bf(b.x); u.s[5] = f2bf(b.y); u.s[6] = f2bf(b.z); u.s[7] = f2bf(b.w);
    return u.v;
}

// ===========================================================================
// Shared device phase helpers (used by both fused and fallback kernels)
// ===========================================================================
__device__ __forceinline__ void wprep_body(int vb, int vt,
        const float* __restrict__ convW, const float* __restrict__ linW,
        const float* __restrict__ finW, const int* __restrict__ om,
        unsigned short* __restrict__ Wt, unsigned short* __restrict__ Wlt,
        unsigned short* __restrict__ Wft, unsigned short* __restrict__ Hb,
        int* __restrict__ rngAll) {
    if (vb < 108) {
        if (vb == 0 && vt < 64)
            ((unsigned*)(Hb + (size_t)NN * CIN))[vt] = 0u;
        const int m = vt >> 3;
        const int c0 = (vt & 7) * 4;
        const float4 wv = *(const float4*)(convW + ((size_t)vb * CPATH + m) * CPATH + c0);
        unsigned short* o = Wt + (size_t)vb * CPATH * CPATH;
        o[(c0 + 0) * CPATH + m] = f2bf(wv.x);
        o[(c0 + 1) * CPATH + m] = f2bf(wv.y);
        o[(c0 + 2) * CPATH + m] = f2bf(wv.z);
        o[(c0 + 3) * CPATH + m] = f2bf(wv.w);
    } else if (vb < 112) {
        const int col = (vb - 108) * 32 + (vt >> 3);
        const int p = col >> 5, c = col & 31;
        const int k0 = (vt & 7) * 16;
        for (int k = k0; k < k0 + 16; k++)
            Wlt[col * CIN + k] = f2bf(linW[(size_t)p * CIN * CPATH + k * CPATH + c]);
    } else if (vb < 116) {
        const int col = (vb - 112) * 32 + (vt >> 3);
        const int k0 = (vt & 7) * 16;
        for (int k = k0; k < k0 + 16; k++)
            Wft[col * CIN + k] = f2bf(finW[(size_t)k * CIN + col]);
    } else {
        const int idx = (vb - 116) * 256 + vt;   // pk*(NTILE+1) + tile
        if (idx < NPATH * NK * (NTILE + 1)) {
            const int tile = idx % (NTILE + 1);
            const int pk = idx / (NTILE + 1);
            const int bound = tile * TJ;
            const int* o = om + (size_t)pk * NN;
            int lo = 0, hi = NN;
            while (lo < hi) {
                const int mid = (lo + hi) >> 1;
                if (o[mid] < bound) lo = mid + 1; else hi = mid;
            }
            rngAll[idx] = lo;
        }
    }
}

__device__ __forceinline__ void lin_body(int row, int mrow, int kq,
        const float* __restrict__ feats, const unsigned short* __restrict__ Wlt,
        const float* __restrict__ linb, unsigned short* __restrict__ Hb) {
    fx4 acc[8];
#pragma unroll
    for (int g = 0; g < 8; g++) acc[g] = (fx4){0.f, 0.f, 0.f, 0.f};
#pragma unroll
    for (int kt = 0; kt < 4; ++kt) {
        const float4 y0 = *(const float4*)(feats + (size_t)row * CIN + kt * 32 + kq * 8);
        const float4 y1 = *(const float4*)(feats + (size_t)row * CIN + kt * 32 + kq * 8 + 4);
        const bfx8 yf = pack_bf8(y0, y1);
#pragma unroll
        for (int g = 0; g < 8; g++) {
            const bfx8 xf = *(const bfx8*)(Wlt + (size_t)(g * 16 + mrow) * CIN + kt * 32 + kq * 8);
            acc[g] = __builtin_amdgcn_mfma_f32_16x16x32_bf16(xf, yf, acc[g], 0, 0, 0);
        }
    }
#pragma unroll
    for (int g = 0; g < 8; g++) {
        const int c0 = g * 16 + kq * 4;
        const float4 bb = *(const float4*)(linb + c0);
        union { unsigned short s[4]; ushort4 v; } u;
        u.s[0] = f2bf(acc[g][0] + bb.x);
        u.s[1] = f2bf(acc[g][1] + bb.y);
        u.s[2] = f2bf(acc[g][2] + bb.z);
        u.s[3] = f2bf(acc[g][3] + bb.w);
        *(ushort4*)(Hb + (size_t)row * CIN + c0) = u.v;
    }
}

__device__ __forceinline__ void fin_body(int row, int mrow, int kq,
        const unsigned short* __restrict__ Cbh, const float* __restrict__ ss,
        const unsigned short* __restrict__ Wft, const float* __restrict__ finb,
        const float* __restrict__ feats, float* __restrict__ out) {
    fx4 acc[8];
#pragma unroll
    for (int g = 0; g < 8; g++) acc[g] = (fx4){0.f, 0.f, 0.f, 0.f};
#pragma unroll
    for (int kt = 0; kt < 4; ++kt) {
        const int k0 = kt * 32 + kq * 8;
        union { unsigned short s[8]; bfx8 v; } cb;
        cb.v = *(const bfx8*)(Cbh + (size_t)row * CIN + k0);
        const float4 sc0 = *(const float4*)(ss + k0);
        const float4 sc1 = *(const float4*)(ss + k0 + 4);
        const float4 sh0 = *(const float4*)(ss + 128 + k0);
        const float4 sh1 = *(const float4*)(ss + 128 + k0 + 4);
        float4 a, bb;
        a.x = fmaxf(fmaf(bf2f(cb.s[0]), sc0.x, sh0.x), 0.f);
        a.y = fmaxf(fmaf(bf2f(cb.s[1]), sc0.y, sh0.y), 0.f);
        a.z = fmaxf(fmaf(bf2f(cb.s[2]), sc0.z, sh0.z), 0.f);
        a.w = fmaxf(fmaf(bf2f(cb.s[3]), sc0.w, sh0.w), 0.f);
        bb.x = fmaxf(fmaf(bf2f(cb.s[4]), sc1.x, sh1.x), 0.f);
        bb.y = fmaxf(fmaf(bf2f(cb.s[5]), sc1.y, sh1.y), 0.f);
        bb.z = fmaxf(fmaf(bf2f(cb.s[6]), sc1.z, sh1.z), 0.f);
        bb.w = fmaxf(fmaf(bf2f(cb.s[7]), sc1.w, sh1.w), 0.f);
        const bfx8 yf = pack_bf8(a, bb);
#pragma unroll
        for (int g = 0; g < 8; g++) {
            const bfx8 xf = *(const bfx8*)(Wft + (size_t)(g * 16 + mrow) * CIN + kt * 32 + kq * 8);
            acc[g] = __builtin_amdgcn_mfma_f32_16x16x32_bf16(xf, yf, acc[g], 0, 0, 0);
        }
    }
#pragma unroll
    for (int g = 0; g < 8; g++) {
        const int c0 = g * 16 + kq * 4;
        const float4 fb = *(const float4*)(finb + c0);
        const float4 rs = *(const float4*)(feats + (size_t)row * CIN + c0);
        float4 o;
        o.x = acc[g][0] + fb.x + rs.x;
        o.y = acc[g][1] + fb.y + rs.y;
        o.z = acc[g][2] + fb.z + rs.z;
        o.w = acc[g][3] + fb.w + rs.w;
        *(float4*)(out + (size_t)row * CIN + c0) = o;
    }
}

// sconv LDS layout (shared struct between fused and fallback)
struct SconvLds {
    int accI[TJ + 1][33];
    int rng[NK][2];
    int gk[MAXG], gt[MAXG];
    int gbase[NK];
    int Gs;
    float redS[32][32], redQ[32][32];
};

__device__ __forceinline__ void sconv_body(SconvLds* sh, int p, int T,
        int tid, int w, int mrow, int kq,
        const unsigned short* __restrict__ Hb, const unsigned short* __restrict__ Wt,
        const int* __restrict__ im, const int* __restrict__ om,
        const int* __restrict__ rngAll, unsigned short* __restrict__ Cbh,
        float* __restrict__ part) {
    const int j0 = T * TJ;
    for (int idx = tid; idx < (TJ + 1) * 33; idx += 512)
        (&sh->accI[0][0])[idx] = 0;
    if (tid < NK * 2) {
        const int k = tid >> 1, which = tid & 1;
        sh->rng[k][which] = rngAll[((size_t)p * NK + k) * (NTILE + 1) + T + which];
    }
    __syncthreads();
    if (tid == 0) {
        int sum = 0;
#pragma unroll
        for (int k = 0; k < NK; k++) {
            sh->gbase[k] = sum;
            if (k != 13)
                sum += (sh->rng[k][1] - sh->rng[k][0] + 15) >> 4;
        }
        sh->Gs = sum;
    }
    __syncthreads();
    if (tid < NK && tid != 13) {
        const int k = tid;
        const int s = sh->rng[k][0];
        const int n = (sh->rng[k][1] - s + 15) >> 4;
        const int bb = sh->gbase[k];
        for (int g = 0; g < n; g++) {
            sh->gk[bb + g] = k;
            sh->gt[bb + g] = s + g * 16;
        }
    }
    __syncthreads();

    const int G = sh->Gs;
    const unsigned short* Wp = Wt + (size_t)p * NK * 1024 + kq * 8;
    const unsigned short* Hp = Hb + (size_t)p * CPATH + kq * 8;
    const int* omP = om + (size_t)p * NK * NN;
    const int* imP = im + (size_t)p * NK * NN;
    const fx4 z4 = {0.f, 0.f, 0.f, 0.f};

    // dense center tap (k=13, identity map): rows w*32.., 2 frags per wave
    {
        const bfx8 xc0 = *(const bfx8*)(Wp + (size_t)13 * 1024 + mrow * CPATH);
        const bfx8 xc1 = *(const bfx8*)(Wp + (size_t)13 * 1024 + (16 + mrow) * CPATH);
        const int r0 = w * 32 + mrow;
        const bfx8 yc0 = *(const bfx8*)(Hp + (size_t)(j0 + r0     ) * CIN);
        const bfx8 yc1 = *(const bfx8*)(Hp + (size_t)(j0 + r0 + 16) * CIN);
        const fx4 e00 = __builtin_amdgcn_mfma_f32_16x16x32_bf16(xc0, yc0, z4, 0, 0, 0);
        const fx4 e01 = __builtin_amdgcn_mfma_f32_16x16x32_bf16(xc1, yc0, z4, 0, 0, 0);
        const fx4 e10 = __builtin_amdgcn_mfma_f32_16x16x32_bf16(xc0, yc1, z4, 0, 0, 0);
        const fx4 e11 = __builtin_amdgcn_mfma_f32_16x16x32_bf16(xc1, yc1, z4, 0, 0, 0);
#pragma unroll
        for (int r = 0; r < 4; r++) {
            atomicAdd(&sh->accI[r0     ][kq * 4 + r],      (int)rintf(e00[r] * SCALE_F));
            atomicAdd(&sh->accI[r0     ][16 + kq * 4 + r], (int)rintf(e01[r] * SCALE_F));
            atomicAdd(&sh->accI[r0 + 16][kq * 4 + r],      (int)rintf(e10[r] * SCALE_F));
            atomicAdd(&sh->accI[r0 + 16][16 + kq * 4 + r], (int)rintf(e11[r] * SCALE_F));
        }
    }

    // scattered phase: 26 off-center taps, 2 groups per wave-iter
    for (int base = 2 * w; base < G; base += 16) {
        const int kA = sh->gk[base];
        const int tA = sh->gt[base] + mrow;
        int kB = 0, tB = NN + mrow;
        if (base + 1 < G) { kB = sh->gk[base + 1]; tB = sh->gt[base + 1] + mrow; }
        const bool vA = tA < sh->rng[kA][1], vB = tB < sh->rng[kB][1];
        const int jjA = vA ? (omP[(size_t)kA * NN + tA] - j0) : TJ;
        const int iA  = vA ? imP[(size_t)kA * NN + tA] : NN;
        const int jjB = vB ? (omP[(size_t)kB * NN + tB] - j0) : TJ;
        const int iB  = vB ? imP[(size_t)kB * NN + tB] : NN;
        const bfx8 yA = *(const bfx8*)(Hp + (size_t)iA * CIN);
        const bfx8 yB = *(const bfx8*)(Hp + (size_t)iB * CIN);
        const bfx8 xa0 = *(const bfx8*)(Wp + (size_t)kA * 1024 + mrow * CPATH);
        const bfx8 xb0 = *(const bfx8*)(Wp + (size_t)kA * 1024 + (16 + mrow) * CPATH);
        const bfx8 xa1 = *(const bfx8*)(Wp + (size_t)kB * 1024 + mrow * CPATH);
        const bfx8 xb1 = *(const bfx8*)(Wp + (size_t)kB * 1024 + (16 + mrow) * CPATH);
        const fx4 dA0 = __builtin_amdgcn_mfma_f32_16x16x32_bf16(xa0, yA, z4, 0, 0, 0);
        const fx4 dA1 = __builtin_amdgcn_mfma_f32_16x16x32_bf16(xb0, yA, z4, 0, 0, 0);
        const fx4 dB0 = __builtin_amdgcn_mfma_f32_16x16x32_bf16(xa1, yB, z4, 0, 0, 0);
        const fx4 dB1 = __builtin_amdgcn_mfma_f32_16x16x32_bf16(xb1, yB, z4, 0, 0, 0);
#pragma unroll
        for (int r = 0; r < 4; r++) {
            atomicAdd(&sh->accI[jjA][kq * 4 + r],      (int)rintf(dA0[r] * SCALE_F));
            atomicAdd(&sh->accI[jjA][16 + kq * 4 + r], (int)rintf(dA1[r] * SCALE_F));
            atomicAdd(&sh->accI[jjB][kq * 4 + r],      (int)rintf(dB0[r] * SCALE_F));
            atomicAdd(&sh->accI[jjB][16 + kq * 4 + r], (int)rintf(dB1[r] * SCALE_F));
        }
    }
    __syncthreads();

    // Phase C: int -> f32, BN partials, packed bf16x2 writeback
    {
        const int c0 = (tid & 15) * 2;
        const int rg = tid >> 4;      // 0..31
        float s0 = 0.f, q0 = 0.f, s1 = 0.f, q1 = 0.f;
        for (int m = 0; m < 8; m++) {
            const int r = rg + 32 * m;
            const float f0 = (float)sh->accI[r][c0] * INV_SCALE;
            const float f1 = (float)sh->accI[r][c0 + 1] * INV_SCALE;
            s0 += f0; q0 = fmaf(f0, f0, q0);
            s1 += f1; q1 = fmaf(f1, f1, q1);
            const unsigned pk2 = (unsigned)f2bf(f0) | ((unsigned)f2bf(f1) << 16);
            *(unsigned*)(Cbh + (size_t)(j0 + r) * CIN + p * CPATH + c0) = pk2;
        }
        sh->redS[rg][c0] = s0; sh->redS[rg][c0 + 1] = s1;
        sh->redQ[rg][c0] = q0; sh->redQ[rg][c0 + 1] = q1;
    }
    __syncthreads();
    if (tid < 32) {
        float s = 0.f;
#pragma unroll
        for (int g = 0; g < 32; g++) s += sh->redS[g][tid];
        part[(((size_t)p * NTILE) + T) * 64 + tid] = s;
    } else if (tid < 64) {
        const int c = tid - 32;
        float q = 0.f;
#pragma unroll
        for (int g = 0; g < 32; g++) q += sh->redQ[g][c];
        part[(((size_t)p * NTILE) + T) * 64 + 32 + c] = q;
    }
}

// ===========================================================================
// Fused cooperative kernel
// ===========================================================================
__global__ void __launch_bounds__(512, 4)
fused(const float* __restrict__ feats, const float* __restrict__ linW,
      const float* __restrict__ linb, const float* __restrict__ convW,
      const float* __restrict__ gamma, const float* __restrict__ beta,
      const float* __restrict__ finW, const float* __restrict__ finb,
      const int* __restrict__ im, const int* __restrict__ om,
      float* __restrict__ out,
      unsigned short* __restrict__ Hb, unsigned short* __restrict__ Cbh,
      unsigned short* __restrict__ Wt, unsigned short* __restrict__ Wlt,
      unsigned short* __restrict__ Wft, int* __restrict__ rngAll,
      float* __restrict__ part, float* __restrict__ ss) {
    cg::grid_group grid = cg::this_grid();

    __shared__ union {
        SconvLds s2;                                    // ~44 KB
        struct { float rs[4][128], rq[4][128]; } s3;    // 4 KB
    } sh;

    const int b = blockIdx.x;          // 0..511
    const int tid = threadIdx.x;       // 0..511
    const int lane = tid & 63;
    const int w = tid >> 6;            // 0..7
    const int mrow = lane & 15, kq = lane >> 4;

    // P0: weight transposes + rng searches
    {
        const int g = b * 512 + tid;
        wprep_body(g >> 8, g & 255, convW, linW, finW, om, Wt, Wlt, Wft, Hb, rngAll);
    }
    grid.sync();

    // P1: lin -> Hb (128 rows per block)
    lin_body(b * 128 + w * 16 + mrow, mrow, kq, feats, Wlt, linb, Hb);
    grid.sync();

    // P2: sconv, two (p,T) pairs per block
    for (int it = 0; it < 2; ++it) {
        const int pair = b + it * 512;       // 0..1023
        sconv_body(&sh.s2, pair >> 8, pair & 255, tid, w, mrow, kq,
                   Hb, Wt, im, om, rngAll, Cbh, part);
        __syncthreads();
    }
    grid.sync();

    // P3: BN finalize (block 0)
    if (b == 0) {
        const int c = tid & 127;
        const int ch = tid >> 7;
        const int p = c >> 5, cc = c & 31;
        float s = 0.f, s2 = 0.f;
        for (int t = ch * (NTILE / 4); t < (ch + 1) * (NTILE / 4); t++) {
            s += part[(((size_t)p * NTILE) + t) * 64 + cc];
            s2 += part[(((size_t)p * NTILE) + t) * 64 + 32 + cc];
        }
        sh.s3.rs[ch][c] = s;
        sh.s3.rq[ch][c] = s2;
        __syncthreads();
        if (ch == 0) {
            s = sh.s3.rs[0][c] + sh.s3.rs[1][c] + sh.s3.rs[2][c] + sh.s3.rs[3][c];
            s2 = sh.s3.rq[0][c] + sh.s3.rq[1][c] + sh.s3.rq[2][c] + sh.s3.rq[3][c];
            const float mean = s * (1.f / NN);
            const float var = s2 * (1.f / NN) - mean * mean;
            const float sc = gamma[c] * rsqrtf(var + 1e-5f);
            ss[c] = sc;
            ss[128 + c] = beta[c] - mean * sc;
        }
    }
    grid.sync();

    // P4: fin -> out (128 rows per block)
    fin_body(b * 128 + w * 16 + mrow, mrow, kq, Cbh, ss, Wft, finb, feats, out);
}

// ===========================================================================
// Fallback kernels (r14 pipeline at TJ=256)
// ===========================================================================
__global__ void wprep_k(const float* __restrict__ convW, const float* __restrict__ linW,
                        const float* __restrict__ finW, const int* __restrict__ om,
                        unsigned short* __restrict__ Wt, unsigned short* __restrict__ Wlt,
                        unsigned short* __restrict__ Wft, unsigned short* __restrict__ Hb,
                        int* __restrict__ rngAll) {
    wprep_body(blockIdx.x, threadIdx.x, convW, linW, finW, om, Wt, Wlt, Wft, Hb, rngAll);
}

__global__ void __launch_bounds__(256, 4)
lin_k(const float* __restrict__ feats, const unsigned short* __restrict__ Wlt,
      const float* __restrict__ linb, unsigned short* __restrict__ Hb) {
    const int tid = threadIdx.x;
    const int lane = tid & 63;
    lin_body(blockIdx.x * 64 + (tid >> 6) * 16 + (lane & 15), lane & 15, lane >> 4,
             feats, Wlt, linb, Hb);
}

__global__ void __launch_bounds__(512)
sconv_k(const unsigned short* __restrict__ Hb, const unsigned short* __restrict__ Wt,
        const int* __restrict__ im, const int* __restrict__ om,
        const int* __restrict__ rngAll, unsigned short* __restrict__ Cbh,
        float* __restrict__ part) {
    __shared__ SconvLds sh;
    const int tid = threadIdx.x;
    const int lane = tid & 63;
    sconv_body(&sh, blockIdx.y, blockIdx.x, tid, tid >> 6, lane & 15, lane >> 4,
               Hb, Wt, im, om, rngAll, Cbh, part);
}

__global__ void bn_k(const float* __restrict__ part, const float* __restrict__ gamma,
                     const float* __restrict__ beta, float* __restrict__ ss) {
    __shared__ float rs[4][128], rq[4][128];
    const int c = threadIdx.x & 127;
    const int ch = threadIdx.x >> 7;
    const int p = c >> 5, cc = c & 31;
    float s = 0.f, s2 = 0.f;
    for (int t = ch * (NTILE / 4); t < (ch + 1) * (NTILE / 4); t++) {
        s += part[(((size_t)p * NTILE) + t) * 64 + cc];
        s2 += part[(((size_t)p * NTILE) + t) * 64 + 32 + cc];
    }
    rs[ch][c] = s;
    rq[ch][c] = s2;
    __syncthreads();
    if (ch == 0) {
        s = rs[0][c] + rs[1][c] + rs[2][c] + rs[3][c];
        s2 = rq[0][c] + rq[1][c] + rq[2][c] + rq[3][c];
        const float mean = s * (1.f / NN);
        const float var = s2 * (1.f / NN) - mean * mean;
        const float sc = gamma[c] * rsqrtf(var + 1e-5f);
        ss[c] = sc;
        ss[128 + c] = beta[c] - mean * sc;
    }
}

__global__ void __launch_bounds__(256, 4)
fin_k(const unsigned short* __restrict__ Cbh, const float* __restrict__ ss,
      const unsigned short* __restrict__ Wft, const float* __restrict__ finb,
      const float* __restrict__ feats, float* __restrict__ out) {
    const int tid = threadIdx.x;
    const int lane = tid & 63;
    fin_body(blockIdx.x * 64 + (tid >> 6) * 16 + (lane & 15), lane & 15, lane >> 4,
             Cbh, ss, Wft, finb, feats, out);
}

// ---------------------------------------------------------------------------
extern "C" void kernel_launch(void* const* d_in, const int* in_sizes, int n_in,
                              void* d_out, int out_size, void* d_ws,
                              size_t ws_size, hipStream_t stream) {
    (void)in_sizes; (void)n_in; (void)out_size; (void)ws_size;
    const float* feats = (const float*)d_in[0];
    const float* linW  = (const float*)d_in[1];
    const float* linb  = (const float*)d_in[2];
    const float* convW = (const float*)d_in[3];
    const float* gamma = (const float*)d_in[4];
    const float* beta  = (const float*)d_in[5];
    const float* finW  = (const float*)d_in[6];
    const float* finb  = (const float*)d_in[7];
    const int*   im    = (const int*)d_in[8];
    const int*   om    = (const int*)d_in[9];
    float* out = (float*)d_out;

    char* ws = (char*)d_ws;
    unsigned short* Hb  = (unsigned short*)(ws);            // 16,781,312 (incl sentinel + pad)
    unsigned short* Cbh = (unsigned short*)(ws + 16781312); // 16,777,216
    unsigned short* Wt  = (unsigned short*)(ws + 33558528); //    221,184
    unsigned short* Wlt = (unsigned short*)(ws + 33779712); //     32,768
    unsigned short* Wft = (unsigned short*)(ws + 33812480); //     32,768
    int*   rngAll       = (int*)(ws + 33845248);            //    111,024 -> pad 114,688
    float* part         = (float*)(ws + 33959936);          //    262,144
    float* ss           = (float*)(ws + 34222080);          //      1,024

    void* args[] = {
        (void*)&feats, (void*)&linW, (void*)&linb, (void*)&convW,
        (void*)&gamma, (void*)&beta, (void*)&finW, (void*)&finb,
        (void*)&im, (void*)&om, (void*)&out,
        (void*)&Hb, (void*)&Cbh, (void*)&Wt, (void*)&Wlt, (void*)&Wft,
        (void*)&rngAll, (void*)&part, (void*)&ss
    };
    hipError_t err = hipLaunchCooperativeKernel((const void*)fused, dim3(512),
                                                dim3(512), args, 0, stream);
    if (err != hipSuccess) {
        // fallback: proven 5-kernel pipeline (r14 structure at TJ=256)
        const int rng_total = NPATH * NK * (NTILE + 1);     // 27,756
        const int rng_blocks = (rng_total + 255) / 256;     // 109
        wprep_k<<<116 + rng_blocks, 256, 0, stream>>>(convW, linW, finW, om,
                                                      Wt, Wlt, Wft, Hb, rngAll);
        lin_k<<<1024, 256, 0, stream>>>(feats, Wlt, linb, Hb);
        sconv_k<<<dim3(NTILE, NPATH), 512, 0, stream>>>(Hb, Wt, im, om, rngAll, Cbh, part);
        bn_k<<<1, 512, 0, stream>>>(part, gamma, beta, ss);
        fin_k<<<1024, 256, 0, stream>>>(Cbh, ss, Wft, finb, feats, out);
    }
}

// Round 17
// 90.780 us; speedup vs baseline: 3.6077x; 3.6077x over previous
//
#include <hip/hip_runtime.h>

// ResNeXt sparse-voxel block, MI355X. Round 17 = exact revert to r14 (best
// measured: 91.3 us). Fusion abandoned after r15 (unlaunchable 78KB LDS) and
// r16 (coop-fused ran at 326 us: one launch_bounds register budget across
// phases with different pressure -> VGPR=64, 27MB scratch spill, 4M LDS
// conflicts). r14 structure: wprep+rng precompute -> lin MFMA -> sconv
// (dense center tap + compacted scattered taps, deterministic int32 LDS
// accumulation) -> parallel BN finalize -> fin MFMA with fused BN+ReLU.

#define NN    65536
#define CIN   128
#define CPATH 32
#define NPATH 4
#define NK    27
#define TJ    512
#define NTILE (NN / TJ)    // 128
#define MAXG  288
#define SCALE_F 2097152.0f          // 2^21
#define INV_SCALE 4.76837158203125e-7f

typedef __attribute__((ext_vector_type(8))) short bfx8;
typedef __attribute__((ext_vector_type(4))) float fx4;

__device__ __forceinline__ unsigned short f2bf(float f) {
    unsigned u = __builtin_bit_cast(unsigned, f);
    u += 0x7FFFu + ((u >> 16) & 1u);
    return (unsigned short)(u >> 16);
}
__device__ __forceinline__ float bf2f(unsigned short s) {
    return __builtin_bit_cast(float, (unsigned)s << 16);
}
__device__ __forceinline__ bfx8 pack_bf8(const float4 a, const float4 b) {
    union { unsigned short s[8]; bfx8 v; } u;
    u.s[0] = f2bf(a.x); u.s[1] = f2bf(a.y); u.s[2] = f2bf(a.z); u.s[3] = f2bf(a.w);
    u.s[4] = f2bf(b.x); u.s[5] = f2bf(b.y); u.s[6] = f2bf(b.z); u.s[7] = f2bf(b.w);
    return u.v;
}

// ---------------------------------------------------------------------------
// wprep_rng: b<108: convW -> Wt[p][k][col][kin] bf16 (+ zero Hb sentinel row);
// b in [108,112): linW -> Wlt; b in [112,116): finW -> Wft;
// b >= 116: rngAll[pk][tile] = searchsorted(out_k, tile*TJ), tile=0..NTILE.
// ---------------------------------------------------------------------------
__global__ void wprep_rng(const float* __restrict__ convW,
                          const float* __restrict__ linW,
                          const float* __restrict__ finW,
                          const int* __restrict__ om,
                          unsigned short* __restrict__ Wt,
                          unsigned short* __restrict__ Wlt,
                          unsigned short* __restrict__ Wft,
                          unsigned short* __restrict__ Hb,
                          int* __restrict__ rngAll) {
    const int b = blockIdx.x;
    const int t = threadIdx.x;
    if (b < 108) {
        if (b == 0 && t < 64)
            ((unsigned*)(Hb + (size_t)NN * CIN))[t] = 0u;
        const int m = t >> 3;
        const int c0 = (t & 7) * 4;
        const float4 w = *(const float4*)(convW + ((size_t)b * CPATH + m) * CPATH + c0);
        unsigned short* o = Wt + (size_t)b * CPATH * CPATH;
        o[(c0 + 0) * CPATH + m] = f2bf(w.x);
        o[(c0 + 1) * CPATH + m] = f2bf(w.y);
        o[(c0 + 2) * CPATH + m] = f2bf(w.z);
        o[(c0 + 3) * CPATH + m] = f2bf(w.w);
    } else if (b < 112) {
        const int col = (b - 108) * 32 + (t >> 3);
        const int p = col >> 5, c = col & 31;
        const int k0 = (t & 7) * 16;
        for (int k = k0; k < k0 + 16; k++)
            Wlt[col * CIN + k] = f2bf(linW[(size_t)p * CIN * CPATH + k * CPATH + c]);
    } else if (b < 116) {
        const int col = (b - 112) * 32 + (t >> 3);
        const int k0 = (t & 7) * 16;
        for (int k = k0; k < k0 + 16; k++)
            Wft[col * CIN + k] = f2bf(finW[(size_t)k * CIN + col]);
    } else {
        const int idx = (b - 116) * 256 + t;     // pk*(NTILE+1) + tile
        if (idx < NPATH * NK * (NTILE + 1)) {
            const int tile = idx % (NTILE + 1);
            const int pk = idx / (NTILE + 1);
            const int bound = tile * TJ;
            const int* o = om + (size_t)pk * NN;
            int lo = 0, hi = NN;
            while (lo < hi) {
                const int mid = (lo + hi) >> 1;
                if (o[mid] < bound) lo = mid + 1; else hi = mid;
            }
            rngAll[idx] = lo;
        }
    }
}

// ---------------------------------------------------------------------------
// lin_mfma: Hb[row][c] = bf16(feats[row] @ Wcat[:,c] + linb[c]).
// ---------------------------------------------------------------------------
__global__ void __launch_bounds__(256, 4)
lin_mfma(const float* __restrict__ feats,
         const unsigned short* __restrict__ Wlt,
         const float* __restrict__ linb,
         unsigned short* __restrict__ Hb) {
    const int tid = threadIdx.x;
    const int w = tid >> 6, lane = tid & 63;
    const int mrow = lane & 15, kq = lane >> 4;
    const int row = blockIdx.x * 64 + w * 16 + mrow;

    fx4 acc[8];
#pragma unroll
    for (int g = 0; g < 8; g++) acc[g] = (fx4){0.f, 0.f, 0.f, 0.f};

#pragma unroll
    for (int kt = 0; kt < 4; ++kt) {
        const float4 y0 = *(const float4*)(feats + (size_t)row * CIN + kt * 32 + kq * 8);
        const float4 y1 = *(const float4*)(feats + (size_t)row * CIN + kt * 32 + kq * 8 + 4);
        const bfx8 yf = pack_bf8(y0, y1);
#pragma unroll
        for (int g = 0; g < 8; g++) {
            const bfx8 xf = *(const bfx8*)(Wlt + (size_t)(g * 16 + mrow) * CIN + kt * 32 + kq * 8);
            acc[g] = __builtin_amdgcn_mfma_f32_16x16x32_bf16(xf, yf, acc[g], 0, 0, 0);
        }
    }
#pragma unroll
    for (int g = 0; g < 8; g++) {
        const int c0 = g * 16 + kq * 4;
        const float4 bb = *(const float4*)(linb + c0);
        union { unsigned short s[4]; ushort4 v; } u;
        u.s[0] = f2bf(acc[g][0] + bb.x);
        u.s[1] = f2bf(acc[g][1] + bb.y);
        u.s[2] = f2bf(acc[g][2] + bb.z);
        u.s[3] = f2bf(acc[g][3] + bb.w);
        *(ushort4*)(Hb + (size_t)row * CIN + c0) = u.v;
    }
}

// ---------------------------------------------------------------------------
// sconv14: dense center tap (k=13, identity map: coalesced, no map loads)
// + compacted scattered loop over the 26 off-center taps.
// Deterministic int32 LDS accumulation throughout.
// ---------------------------------------------------------------------------
__global__ void __launch_bounds__(512)
sconv14(const unsigned short* __restrict__ Hb,
        const unsigned short* __restrict__ Wt,
        const int* __restrict__ im,
        const int* __restrict__ om,
        const int* __restrict__ rngAll,
        unsigned short* __restrict__ Cbh,
        float* __restrict__ part) {
    __shared__ int accI[TJ + 1][33];      // +1 dump row; stride 33 = bank-safe
    __shared__ int rng[NK][2];
    __shared__ int gkA[MAXG], gtA[MAXG];
    __shared__ int gbase[NK];
    __shared__ int Gs;
    __shared__ float redS[32][32], redQ[32][32];

    const int p = blockIdx.y;
    const int T = blockIdx.x;
    const int j0 = T * TJ;
    const int tid = threadIdx.x;
    const int lane = tid & 63;
    const int w = tid >> 6;
    const int mrow = lane & 15, kq = lane >> 4;

    for (int idx = tid; idx < (TJ + 1) * 33; idx += 512)
        (&accI[0][0])[idx] = 0;
    if (tid < NK * 2) {
        const int k = tid >> 1, which = tid & 1;
        rng[k][which] = rngAll[((size_t)p * NK + k) * (NTILE + 1) + T + which];
    }
    __syncthreads();
    if (tid == 0) {
        int sum = 0;
#pragma unroll
        for (int k = 0; k < NK; k++) {
            gbase[k] = sum;
            if (k != 13)                      // center handled densely
                sum += (rng[k][1] - rng[k][0] + 15) >> 4;
        }
        Gs = sum;
    }
    __syncthreads();
    if (tid < NK && tid != 13) {
        const int k = tid;
        const int s = rng[k][0];
        const int n = (rng[k][1] - s + 15) >> 4;
        const int b = gbase[k];
        for (int g = 0; g < n; g++) {
            gkA[b + g] = k;
            gtA[b + g] = s + g * 16;
        }
    }
    __syncthreads();

    const int G = Gs;
    const unsigned short* Wp = Wt + (size_t)p * NK * 1024 + kq * 8;
    const unsigned short* Hp = Hb + (size_t)p * CPATH + kq * 8;
    const int* omP = om + (size_t)p * NK * NN;
    const int* imP = im + (size_t)p * NK * NN;
    const fx4 z4 = {0.f, 0.f, 0.f, 0.f};

    // ---- dense center phase: rows w*64 .. w*64+63, coalesced ----
    {
        const bfx8 xc0 = *(const bfx8*)(Wp + (size_t)13 * 1024 + mrow * CPATH);
        const bfx8 xc1 = *(const bfx8*)(Wp + (size_t)13 * 1024 + (16 + mrow) * CPATH);
        const int r0 = w * 64 + mrow;
        const bfx8 yc0 = *(const bfx8*)(Hp + (size_t)(j0 + r0     ) * CIN);
        const bfx8 yc1 = *(const bfx8*)(Hp + (size_t)(j0 + r0 + 16) * CIN);
        const bfx8 yc2 = *(const bfx8*)(Hp + (size_t)(j0 + r0 + 32) * CIN);
        const bfx8 yc3 = *(const bfx8*)(Hp + (size_t)(j0 + r0 + 48) * CIN);
        const fx4 e00 = __builtin_amdgcn_mfma_f32_16x16x32_bf16(xc0, yc0, z4, 0, 0, 0);
        const fx4 e01 = __builtin_amdgcn_mfma_f32_16x16x32_bf16(xc1, yc0, z4, 0, 0, 0);
        const fx4 e10 = __builtin_amdgcn_mfma_f32_16x16x32_bf16(xc0, yc1, z4, 0, 0, 0);
        const fx4 e11 = __builtin_amdgcn_mfma_f32_16x16x32_bf16(xc1, yc1, z4, 0, 0, 0);
        const fx4 e20 = __builtin_amdgcn_mfma_f32_16x16x32_bf16(xc0, yc2, z4, 0, 0, 0);
        const fx4 e21 = __builtin_amdgcn_mfma_f32_16x16x32_bf16(xc1, yc2, z4, 0, 0, 0);
        const fx4 e30 = __builtin_amdgcn_mfma_f32_16x16x32_bf16(xc0, yc3, z4, 0, 0, 0);
        const fx4 e31 = __builtin_amdgcn_mfma_f32_16x16x32_bf16(xc1, yc3, z4, 0, 0, 0);
#pragma unroll
        for (int r = 0; r < 4; r++) {
            atomicAdd(&accI[r0     ][kq * 4 + r],      (int)rintf(e00[r] * SCALE_F));
            atomicAdd(&accI[r0     ][16 + kq * 4 + r], (int)rintf(e01[r] * SCALE_F));
            atomicAdd(&accI[r0 + 16][kq * 4 + r],      (int)rintf(e10[r] * SCALE_F));
            atomicAdd(&accI[r0 + 16][16 + kq * 4 + r], (int)rintf(e11[r] * SCALE_F));
            atomicAdd(&accI[r0 + 32][kq * 4 + r],      (int)rintf(e20[r] * SCALE_F));
            atomicAdd(&accI[r0 + 32][16 + kq * 4 + r], (int)rintf(e21[r] * SCALE_F));
            atomicAdd(&accI[r0 + 48][kq * 4 + r],      (int)rintf(e30[r] * SCALE_F));
            atomicAdd(&accI[r0 + 48][16 + kq * 4 + r], (int)rintf(e31[r] * SCALE_F));
        }
    }

    // ---- scattered phase: 26 off-center taps ----
    for (int base = 4 * w; base < G; base += 32) {
        int kk0 = 0, kk1 = 0, kk2 = 0, kk3 = 0;
        int tt0 = NN + mrow, tt1 = NN + mrow, tt2 = NN + mrow, tt3 = NN + mrow;
        kk0 = gkA[base]; tt0 = gtA[base] + mrow;
        if (base + 1 < G) { kk1 = gkA[base + 1]; tt1 = gtA[base + 1] + mrow; }
        if (base + 2 < G) { kk2 = gkA[base + 2]; tt2 = gtA[base + 2] + mrow; }
        if (base + 3 < G) { kk3 = gkA[base + 3]; tt3 = gtA[base + 3] + mrow; }
        const bool v0 = tt0 < rng[kk0][1], v1 = tt1 < rng[kk1][1];
        const bool v2 = tt2 < rng[kk2][1], v3 = tt3 < rng[kk3][1];
        const int jj0 = v0 ? (omP[(size_t)kk0 * NN + tt0] - j0) : TJ;
        const int ii0 = v0 ? imP[(size_t)kk0 * NN + tt0] : NN;
        const int jj1 = v1 ? (omP[(size_t)kk1 * NN + tt1] - j0) : TJ;
        const int ii1 = v1 ? imP[(size_t)kk1 * NN + tt1] : NN;
        const int jj2 = v2 ? (omP[(size_t)kk2 * NN + tt2] - j0) : TJ;
        const int ii2 = v2 ? imP[(size_t)kk2 * NN + tt2] : NN;
        const int jj3 = v3 ? (omP[(size_t)kk3 * NN + tt3] - j0) : TJ;
        const int ii3 = v3 ? imP[(size_t)kk3 * NN + tt3] : NN;
        const bfx8 y0 = *(const bfx8*)(Hp + (size_t)ii0 * CIN);
        const bfx8 y1 = *(const bfx8*)(Hp + (size_t)ii1 * CIN);
        const bfx8 y2 = *(const bfx8*)(Hp + (size_t)ii2 * CIN);
        const bfx8 y3 = *(const bfx8*)(Hp + (size_t)ii3 * CIN);
        const bfx8 xa0 = *(const bfx8*)(Wp + (size_t)kk0 * 1024 + mrow * CPATH);
        const bfx8 xb0 = *(const bfx8*)(Wp + (size_t)kk0 * 1024 + (16 + mrow) * CPATH);
        const bfx8 xa1 = *(const bfx8*)(Wp + (size_t)kk1 * 1024 + mrow * CPATH);
        const bfx8 xb1 = *(const bfx8*)(Wp + (size_t)kk1 * 1024 + (16 + mrow) * CPATH);
        const bfx8 xa2 = *(const bfx8*)(Wp + (size_t)kk2 * 1024 + mrow * CPATH);
        const bfx8 xb2 = *(const bfx8*)(Wp + (size_t)kk2 * 1024 + (16 + mrow) * CPATH);
        const bfx8 xa3 = *(const bfx8*)(Wp + (size_t)kk3 * 1024 + mrow * CPATH);
        const bfx8 xb3 = *(const bfx8*)(Wp + (size_t)kk3 * 1024 + (16 + mrow) * CPATH);
        const fx4 d00 = __builtin_amdgcn_mfma_f32_16x16x32_bf16(xa0, y0, z4, 0, 0, 0);
        const fx4 d01 = __builtin_amdgcn_mfma_f32_16x16x32_bf16(xb0, y0, z4, 0, 0, 0);
        const fx4 d10 = __builtin_amdgcn_mfma_f32_16x16x32_bf16(xa1, y1, z4, 0, 0, 0);
        const fx4 d11 = __builtin_amdgcn_mfma_f32_16x16x32_bf16(xb1, y1, z4, 0, 0, 0);
        const fx4 d20 = __builtin_amdgcn_mfma_f32_16x16x32_bf16(xa2, y2, z4, 0, 0, 0);
        const fx4 d21 = __builtin_amdgcn_mfma_f32_16x16x32_bf16(xb2, y2, z4, 0, 0, 0);
        const fx4 d30 = __builtin_amdgcn_mfma_f32_16x16x32_bf16(xa3, y3, z4, 0, 0, 0);
        const fx4 d31 = __builtin_amdgcn_mfma_f32_16x16x32_bf16(xb3, y3, z4, 0, 0, 0);
#pragma unroll
        for (int r = 0; r < 4; r++) {
            atomicAdd(&accI[jj0][kq * 4 + r],      (int)rintf(d00[r] * SCALE_F));
            atomicAdd(&accI[jj0][16 + kq * 4 + r], (int)rintf(d01[r] * SCALE_F));
            atomicAdd(&accI[jj1][kq * 4 + r],      (int)rintf(d10[r] * SCALE_F));
            atomicAdd(&accI[jj1][16 + kq * 4 + r], (int)rintf(d11[r] * SCALE_F));
            atomicAdd(&accI[jj2][kq * 4 + r],      (int)rintf(d20[r] * SCALE_F));
            atomicAdd(&accI[jj2][16 + kq * 4 + r], (int)rintf(d21[r] * SCALE_F));
            atomicAdd(&accI[jj3][kq * 4 + r],      (int)rintf(d30[r] * SCALE_F));
            atomicAdd(&accI[jj3][16 + kq * 4 + r], (int)rintf(d31[r] * SCALE_F));
        }
    }
    __syncthreads();

    // Phase C: int -> f32, BN partials, packed bf16x2 writeback.
    {
        const int c0 = (tid & 15) * 2;
        const int rg = tid >> 4;          // 0..31
        float s0 = 0.f, q0 = 0.f, s1 = 0.f, q1 = 0.f;
        for (int m = 0; m < 16; m++) {
            const int r = rg + 32 * m;
            const float f0 = (float)accI[r][c0] * INV_SCALE;
            const float f1 = (float)accI[r][c0 + 1] * INV_SCALE;
            s0 += f0; q0 = fmaf(f0, f0, q0);
            s1 += f1; q1 = fmaf(f1, f1, q1);
            const unsigned pk2 = (unsigned)f2bf(f0) | ((unsigned)f2bf(f1) << 16);
            *(unsigned*)(Cbh + (size_t)(j0 + r) * CIN + p * CPATH + c0) = pk2;
        }
        redS[rg][c0] = s0; redS[rg][c0 + 1] = s1;
        redQ[rg][c0] = q0; redQ[rg][c0 + 1] = q1;
    }
    __syncthreads();
    if (tid < 32) {
        float s = 0.f;
#pragma unroll
        for (int g = 0; g < 32; g++) s += redS[g][tid];
        part[(((size_t)p * NTILE) + T) * 64 + tid] = s;
    } else if (tid < 64) {
        const int c = tid - 32;
        float q = 0.f;
#pragma unroll
        for (int g = 0; g < 32; g++) q += redQ[g][c];
        part[(((size_t)p * NTILE) + T) * 64 + 32 + c] = q;
    }
}

// ---------------------------------------------------------------------------
// BN finalize, parallel: 512 thr = 4 tile-chunks x 128 channels.
// ---------------------------------------------------------------------------
__global__ void bn_stats2(const float* __restrict__ part,
                          const float* __restrict__ gamma,
                          const float* __restrict__ beta,
                          float* __restrict__ ss) {
    __shared__ float rs[4][128], rq[4][128];
    const int c = threadIdx.x & 127;
    const int ch = threadIdx.x >> 7;      // 0..3
    const int p = c >> 5, cc = c & 31;
    float s = 0.f, s2 = 0.f;
    for (int t = ch * (NTILE / 4); t < (ch + 1) * (NTILE / 4); t++) {
        s += part[(((size_t)p * NTILE) + t) * 64 + cc];
        s2 += part[(((size_t)p * NTILE) + t) * 64 + 32 + cc];
    }
    rs[ch][c] = s;
    rq[ch][c] = s2;
    __syncthreads();
    if (ch == 0) {
        s = rs[0][c] + rs[1][c] + rs[2][c] + rs[3][c];
        s2 = rq[0][c] + rq[1][c] + rq[2][c] + rq[3][c];
        const float mean = s * (1.f / NN);
        const float var = s2 * (1.f / NN) - mean * mean;
        const float sc = gamma[c] * rsqrtf(var + 1e-5f);
        ss[c] = sc;
        ss[128 + c] = beta[c] - mean * sc;
    }
}

// ---------------------------------------------------------------------------
// fin_mfma: out = relu(norm(Cbh)) @ finW + finb + feats.
// ---------------------------------------------------------------------------
__global__ void __launch_bounds__(256, 4)
fin_mfma(const unsigned short* __restrict__ Cbh,
         const float* __restrict__ ss,
         const unsigned short* __restrict__ Wft,
         const float* __restrict__ finb,
         const float* __restrict__ feats,
         float* __restrict__ out) {
    const int tid = threadIdx.x;
    const int w = tid >> 6, lane = tid & 63;
    const int mrow = lane & 15, kq = lane >> 4;
    const int row = blockIdx.x * 64 + w * 16 + mrow;

    fx4 acc[8];
#pragma unroll
    for (int g = 0; g < 8; g++) acc[g] = (fx4){0.f, 0.f, 0.f, 0.f};

#pragma unroll
    for (int kt = 0; kt < 4; ++kt) {
        const int k0 = kt * 32 + kq * 8;
        union { unsigned short s[8]; bfx8 v; } cb;
        cb.v = *(const bfx8*)(Cbh + (size_t)row * CIN + k0);
        const float4 sc0 = *(const float4*)(ss + k0);
        const float4 sc1 = *(const float4*)(ss + k0 + 4);
        const float4 sh0 = *(const float4*)(ss + 128 + k0);
        const float4 sh1 = *(const float4*)(ss + 128 + k0 + 4);
        float4 a, b;
        a.x = fmaxf(fmaf(bf2f(cb.s[0]), sc0.x, sh0.x), 0.f);
        a.y = fmaxf(fmaf(bf2f(cb.s[1]), sc0.y, sh0.y), 0.f);
        a.z = fmaxf(fmaf(bf2f(cb.s[2]), sc0.z, sh0.z), 0.f);
        a.w = fmaxf(fmaf(bf2f(cb.s[3]), sc0.w, sh0.w), 0.f);
        b.x = fmaxf(fmaf(bf2f(cb.s[4]), sc1.x, sh1.x), 0.f);
        b.y = fmaxf(fmaf(bf2f(cb.s[5]), sc1.y, sh1.y), 0.f);
        b.z = fmaxf(fmaf(bf2f(cb.s[6]), sc1.z, sh1.z), 0.f);
        b.w = fmaxf(fmaf(bf2f(cb.s[7]), sc1.w, sh1.w), 0.f);
        const bfx8 yf = pack_bf8(a, b);
#pragma unroll
        for (int g = 0; g < 8; g++) {
            const bfx8 xf = *(const bfx8*)(Wft + (size_t)(g * 16 + mrow) * CIN + kt * 32 + kq * 8);
            acc[g] = __builtin_amdgcn_mfma_f32_16x16x32_bf16(xf, yf, acc[g], 0, 0, 0);
        }
    }
#pragma unroll
    for (int g = 0; g < 8; g++) {
        const int c0 = g * 16 + kq * 4;
        const float4 fb = *(const float4*)(finb + c0);
        const float4 rs = *(const float4*)(feats + (size_t)row * CIN + c0);
        float4 o;
        o.x = acc[g][0] + fb.x + rs.x;
        o.y = acc[g][1] + fb.y + rs.y;
        o.z = acc[g][2] + fb.z + rs.z;
        o.w = acc[g][3] + fb.w + rs.w;
        *(float4*)(out + (size_t)row * CIN + c0) = o;
    }
}

// ---------------------------------------------------------------------------
extern "C" void kernel_launch(void* const* d_in, const int* in_sizes, int n_in,
                              void* d_out, int out_size, void* d_ws,
                              size_t ws_size, hipStream_t stream) {
    (void)in_sizes; (void)n_in; (void)out_size; (void)ws_size;
    const float* feats = (const float*)d_in[0];
    const float* linW  = (const float*)d_in[1];
    const float* linb  = (const float*)d_in[2];
    const float* convW = (const float*)d_in[3];
    const float* gamma = (const float*)d_in[4];
    const float* beta  = (const float*)d_in[5];
    const float* finW  = (const float*)d_in[6];
    const float* finb  = (const float*)d_in[7];
    const int*   im    = (const int*)d_in[8];
    const int*   om    = (const int*)d_in[9];
    float* out = (float*)d_out;

    char* ws = (char*)d_ws;
    unsigned short* Hb  = (unsigned short*)(ws);            // 16,781,312 (incl sentinel row + pad)
    unsigned short* Cbh = (unsigned short*)(ws + 16781312); // 16,777,216
    unsigned short* Wt  = (unsigned short*)(ws + 33558528); //    221,184
    unsigned short* Wlt = (unsigned short*)(ws + 33779712); //     32,768
    unsigned short* Wft = (unsigned short*)(ws + 33812480); //     32,768
    int*   rngAll       = (int*)(ws + 33845248);            //     55,728 -> pad 57,344
    float* part         = (float*)(ws + 33902592);          //    131,072
    float* ss           = (float*)(ws + 34033664);          //      1,024

    const int rng_total = NPATH * NK * (NTILE + 1);         // 13,932
    const int rng_blocks = (rng_total + 255) / 256;         // 55
    wprep_rng<<<116 + rng_blocks, 256, 0, stream>>>(convW, linW, finW, om,
                                                    Wt, Wlt, Wft, Hb, rngAll);
    lin_mfma<<<1024, 256, 0, stream>>>(feats, Wlt, linb, Hb);
    sconv14<<<dim3(NTILE, NPATH), 512, 0, stream>>>(Hb, Wt, im, om, rngAll, Cbh, part);
    bn_stats2<<<1, 512, 0, stream>>>(part, gamma, beta, ss);
    fin_mfma<<<1024, 256, 0, stream>>>(Cbh, ss, Wft, finb, feats, out);
}

// Round 18
// 88.681 us; speedup vs baseline: 3.6931x; 1.0237x over previous
//
#include <hip/hip_runtime.h>

// ResNeXt sparse-voxel block, MI355X. Round 18 = r14/r17 structure with the
// BN-finalize kernel eliminated: sconv Phase C atomically accumulates
// per-channel sum/sumsq as GLOBAL int64 fixed-point (associative -> fully
// deterministic, any block order), and each fin block recomputes the 128
// scale/shift values from the 256 counters into LDS (~1KB, negligible).
// wprep zeros the counters each call. 4 launches instead of 5.

#define NN    65536
#define CIN   128
#define CPATH 32
#define NPATH 4
#define NK    27
#define TJ    512
#define NTILE (NN / TJ)    // 128
#define MAXG  288
#define SCALE_F 2097152.0f          // 2^21
#define INV_SCALE 4.76837158203125e-7f

typedef __attribute__((ext_vector_type(8))) short bfx8;
typedef __attribute__((ext_vector_type(4))) float fx4;
typedef unsigned long long ull;

__device__ __forceinline__ unsigned short f2bf(float f) {
    unsigned u = __builtin_bit_cast(unsigned, f);
    u += 0x7FFFu + ((u >> 16) & 1u);
    return (unsigned short)(u >> 16);
}
__device__ __forceinline__ float bf2f(unsigned short s) {
    return __builtin_bit_cast(float, (unsigned)s << 16);
}
__device__ __forceinline__ bfx8 pack_bf8(const float4 a, const float4 b) {
    union { unsigned short s[8]; bfx8 v; } u;
    u.s[0] = f2bf(a.x); u.s[1] = f2bf(a.y); u.s[2] = f2bf(a.z); u.s[3] = f2bf(a.w);
    u.s[4] = f2bf(b.x); u.s[5] = f2bf(b.y); u.s[6] = f2bf(b.z); u.s[7] = f2bf(b.w);
    return u.v;
}

// ---------------------------------------------------------------------------
// wprep_rng: b<108: convW -> Wt bf16 (+ zero Hb sentinel row);
// b in [108,112): linW -> Wlt (b==108 also zeros the 256 int64 stat counters);
// b in [112,116): finW -> Wft; b >= 116: rngAll searchsorted.
// ---------------------------------------------------------------------------
__global__ void wprep_rng(const float* __restrict__ convW,
                          const float* __restrict__ linW,
                          const float* __restrict__ finW,
                          const int* __restrict__ om,
                          unsigned short* __restrict__ Wt,
                          unsigned short* __restrict__ Wlt,
                          unsigned short* __restrict__ Wft,
                          unsigned short* __restrict__ Hb,
                          int* __restrict__ rngAll,
                          ull* __restrict__ gstat) {
    const int b = blockIdx.x;
    const int t = threadIdx.x;
    if (b < 108) {
        if (b == 0 && t < 64)
            ((unsigned*)(Hb + (size_t)NN * CIN))[t] = 0u;
        const int m = t >> 3;
        const int c0 = (t & 7) * 4;
        const float4 w = *(const float4*)(convW + ((size_t)b * CPATH + m) * CPATH + c0);
        unsigned short* o = Wt + (size_t)b * CPATH * CPATH;
        o[(c0 + 0) * CPATH + m] = f2bf(w.x);
        o[(c0 + 1) * CPATH + m] = f2bf(w.y);
        o[(c0 + 2) * CPATH + m] = f2bf(w.z);
        o[(c0 + 3) * CPATH + m] = f2bf(w.w);
    } else if (b < 112) {
        if (b == 108) gstat[t] = 0ull;    // zero 256 stat counters each call
        const int col = (b - 108) * 32 + (t >> 3);
        const int p = col >> 5, c = col & 31;
        const int k0 = (t & 7) * 16;
        for (int k = k0; k < k0 + 16; k++)
            Wlt[col * CIN + k] = f2bf(linW[(size_t)p * CIN * CPATH + k * CPATH + c]);
    } else if (b < 116) {
        const int col = (b - 112) * 32 + (t >> 3);
        const int k0 = (t & 7) * 16;
        for (int k = k0; k < k0 + 16; k++)
            Wft[col * CIN + k] = f2bf(finW[(size_t)k * CIN + col]);
    } else {
        const int idx = (b - 116) * 256 + t;     // pk*(NTILE+1) + tile
        if (idx < NPATH * NK * (NTILE + 1)) {
            const int tile = idx % (NTILE + 1);
            const int pk = idx / (NTILE + 1);
            const int bound = tile * TJ;
            const int* o = om + (size_t)pk * NN;
            int lo = 0, hi = NN;
            while (lo < hi) {
                const int mid = (lo + hi) >> 1;
                if (o[mid] < bound) lo = mid + 1; else hi = mid;
            }
            rngAll[idx] = lo;
        }
    }
}

// ---------------------------------------------------------------------------
// lin_mfma: Hb[row][c] = bf16(feats[row] @ Wcat[:,c] + linb[c]).
// ---------------------------------------------------------------------------
__global__ void __launch_bounds__(256, 4)
lin_mfma(const float* __restrict__ feats,
         const unsigned short* __restrict__ Wlt,
         const float* __restrict__ linb,
         unsigned short* __restrict__ Hb) {
    const int tid = threadIdx.x;
    const int w = tid >> 6, lane = tid & 63;
    const int mrow = lane & 15, kq = lane >> 4;
    const int row = blockIdx.x * 64 + w * 16 + mrow;

    fx4 acc[8];
#pragma unroll
    for (int g = 0; g < 8; g++) acc[g] = (fx4){0.f, 0.f, 0.f, 0.f};

#pragma unroll
    for (int kt = 0; kt < 4; ++kt) {
        const float4 y0 = *(const float4*)(feats + (size_t)row * CIN + kt * 32 + kq * 8);
        const float4 y1 = *(const float4*)(feats + (size_t)row * CIN + kt * 32 + kq * 8 + 4);
        const bfx8 yf = pack_bf8(y0, y1);
#pragma unroll
        for (int g = 0; g < 8; g++) {
            const bfx8 xf = *(const bfx8*)(Wlt + (size_t)(g * 16 + mrow) * CIN + kt * 32 + kq * 8);
            acc[g] = __builtin_amdgcn_mfma_f32_16x16x32_bf16(xf, yf, acc[g], 0, 0, 0);
        }
    }
#pragma unroll
    for (int g = 0; g < 8; g++) {
        const int c0 = g * 16 + kq * 4;
        const float4 bb = *(const float4*)(linb + c0);
        union { unsigned short s[4]; ushort4 v; } u;
        u.s[0] = f2bf(acc[g][0] + bb.x);
        u.s[1] = f2bf(acc[g][1] + bb.y);
        u.s[2] = f2bf(acc[g][2] + bb.z);
        u.s[3] = f2bf(acc[g][3] + bb.w);
        *(ushort4*)(Hb + (size_t)row * CIN + c0) = u.v;
    }
}

// ---------------------------------------------------------------------------
// sconv15: dense center tap + compacted scattered taps, deterministic int32
// LDS accumulation; per-channel BN stats -> global int64 fixed-point atomics.
// ---------------------------------------------------------------------------
__global__ void __launch_bounds__(512)
sconv15(const unsigned short* __restrict__ Hb,
        const unsigned short* __restrict__ Wt,
        const int* __restrict__ im,
        const int* __restrict__ om,
        const int* __restrict__ rngAll,
        unsigned short* __restrict__ Cbh,
        ull* __restrict__ gstat) {
    __shared__ int accI[TJ + 1][33];      // +1 dump row; stride 33 = bank-safe
    __shared__ int rng[NK][2];
    __shared__ int gkA[MAXG], gtA[MAXG];
    __shared__ int gbase[NK];
    __shared__ int Gs;
    __shared__ float redS[32][32], redQ[32][32];

    const int p = blockIdx.y;
    const int T = blockIdx.x;
    const int j0 = T * TJ;
    const int tid = threadIdx.x;
    const int lane = tid & 63;
    const int w = tid >> 6;
    const int mrow = lane & 15, kq = lane >> 4;

    for (int idx = tid; idx < (TJ + 1) * 33; idx += 512)
        (&accI[0][0])[idx] = 0;
    if (tid < NK * 2) {
        const int k = tid >> 1, which = tid & 1;
        rng[k][which] = rngAll[((size_t)p * NK + k) * (NTILE + 1) + T + which];
    }
    __syncthreads();
    if (tid == 0) {
        int sum = 0;
#pragma unroll
        for (int k = 0; k < NK; k++) {
            gbase[k] = sum;
            if (k != 13)                      // center handled densely
                sum += (rng[k][1] - rng[k][0] + 15) >> 4;
        }
        Gs = sum;
    }
    __syncthreads();
    if (tid < NK && tid != 13) {
        const int k = tid;
        const int s = rng[k][0];
        const int n = (rng[k][1] - s + 15) >> 4;
        const int b = gbase[k];
        for (int g = 0; g < n; g++) {
            gkA[b + g] = k;
            gtA[b + g] = s + g * 16;
        }
    }
    __syncthreads();

    const int G = Gs;
    const unsigned short* Wp = Wt + (size_t)p * NK * 1024 + kq * 8;
    const unsigned short* Hp = Hb + (size_t)p * CPATH + kq * 8;
    const int* omP = om + (size_t)p * NK * NN;
    const int* imP = im + (size_t)p * NK * NN;
    const fx4 z4 = {0.f, 0.f, 0.f, 0.f};

    // ---- dense center phase: rows w*64 .. w*64+63, coalesced ----
    {
        const bfx8 xc0 = *(const bfx8*)(Wp + (size_t)13 * 1024 + mrow * CPATH);
        const bfx8 xc1 = *(const bfx8*)(Wp + (size_t)13 * 1024 + (16 + mrow) * CPATH);
        const int r0 = w * 64 + mrow;
        const bfx8 yc0 = *(const bfx8*)(Hp + (size_t)(j0 + r0     ) * CIN);
        const bfx8 yc1 = *(const bfx8*)(Hp + (size_t)(j0 + r0 + 16) * CIN);
        const bfx8 yc2 = *(const bfx8*)(Hp + (size_t)(j0 + r0 + 32) * CIN);
        const bfx8 yc3 = *(const bfx8*)(Hp + (size_t)(j0 + r0 + 48) * CIN);
        const fx4 e00 = __builtin_amdgcn_mfma_f32_16x16x32_bf16(xc0, yc0, z4, 0, 0, 0);
        const fx4 e01 = __builtin_amdgcn_mfma_f32_16x16x32_bf16(xc1, yc0, z4, 0, 0, 0);
        const fx4 e10 = __builtin_amdgcn_mfma_f32_16x16x32_bf16(xc0, yc1, z4, 0, 0, 0);
        const fx4 e11 = __builtin_amdgcn_mfma_f32_16x16x32_bf16(xc1, yc1, z4, 0, 0, 0);
        const fx4 e20 = __builtin_amdgcn_mfma_f32_16x16x32_bf16(xc0, yc2, z4, 0, 0, 0);
        const fx4 e21 = __builtin_amdgcn_mfma_f32_16x16x32_bf16(xc1, yc2, z4, 0, 0, 0);
        const fx4 e30 = __builtin_amdgcn_mfma_f32_16x16x32_bf16(xc0, yc3, z4, 0, 0, 0);
        const fx4 e31 = __builtin_amdgcn_mfma_f32_16x16x32_bf16(xc1, yc3, z4, 0, 0, 0);
#pragma unroll
        for (int r = 0; r < 4; r++) {
            atomicAdd(&accI[r0     ][kq * 4 + r],      (int)rintf(e00[r] * SCALE_F));
            atomicAdd(&accI[r0     ][16 + kq * 4 + r], (int)rintf(e01[r] * SCALE_F));
            atomicAdd(&accI[r0 + 16][kq * 4 + r],      (int)rintf(e10[r] * SCALE_F));
            atomicAdd(&accI[r0 + 16][16 + kq * 4 + r], (int)rintf(e11[r] * SCALE_F));
            atomicAdd(&accI[r0 + 32][kq * 4 + r],      (int)rintf(e20[r] * SCALE_F));
            atomicAdd(&accI[r0 + 32][16 + kq * 4 + r], (int)rintf(e21[r] * SCALE_F));
            atomicAdd(&accI[r0 + 48][kq * 4 + r],      (int)rintf(e30[r] * SCALE_F));
            atomicAdd(&accI[r0 + 48][16 + kq * 4 + r], (int)rintf(e31[r] * SCALE_F));
        }
    }

    // ---- scattered phase: 26 off-center taps ----
    for (int base = 4 * w; base < G; base += 32) {
        int kk0 = 0, kk1 = 0, kk2 = 0, kk3 = 0;
        int tt0 = NN + mrow, tt1 = NN + mrow, tt2 = NN + mrow, tt3 = NN + mrow;
        kk0 = gkA[base]; tt0 = gtA[base] + mrow;
        if (base + 1 < G) { kk1 = gkA[base + 1]; tt1 = gtA[base + 1] + mrow; }
        if (base + 2 < G) { kk2 = gkA[base + 2]; tt2 = gtA[base + 2] + mrow; }
        if (base + 3 < G) { kk3 = gkA[base + 3]; tt3 = gtA[base + 3] + mrow; }
        const bool v0 = tt0 < rng[kk0][1], v1 = tt1 < rng[kk1][1];
        const bool v2 = tt2 < rng[kk2][1], v3 = tt3 < rng[kk3][1];
        const int jj0 = v0 ? (omP[(size_t)kk0 * NN + tt0] - j0) : TJ;
        const int ii0 = v0 ? imP[(size_t)kk0 * NN + tt0] : NN;
        const int jj1 = v1 ? (omP[(size_t)kk1 * NN + tt1] - j0) : TJ;
        const int ii1 = v1 ? imP[(size_t)kk1 * NN + tt1] : NN;
        const int jj2 = v2 ? (omP[(size_t)kk2 * NN + tt2] - j0) : TJ;
        const int ii2 = v2 ? imP[(size_t)kk2 * NN + tt2] : NN;
        const int jj3 = v3 ? (omP[(size_t)kk3 * NN + tt3] - j0) : TJ;
        const int ii3 = v3 ? imP[(size_t)kk3 * NN + tt3] : NN;
        const bfx8 y0 = *(const bfx8*)(Hp + (size_t)ii0 * CIN);
        const bfx8 y1 = *(const bfx8*)(Hp + (size_t)ii1 * CIN);
        const bfx8 y2 = *(const bfx8*)(Hp + (size_t)ii2 * CIN);
        const bfx8 y3 = *(const bfx8*)(Hp + (size_t)ii3 * CIN);
        const bfx8 xa0 = *(const bfx8*)(Wp + (size_t)kk0 * 1024 + mrow * CPATH);
        const bfx8 xb0 = *(const bfx8*)(Wp + (size_t)kk0 * 1024 + (16 + mrow) * CPATH);
        const bfx8 xa1 = *(const bfx8*)(Wp + (size_t)kk1 * 1024 + mrow * CPATH);
        const bfx8 xb1 = *(const bfx8*)(Wp + (size_t)kk1 * 1024 + (16 + mrow) * CPATH);
        const bfx8 xa2 = *(const bfx8*)(Wp + (size_t)kk2 * 1024 + mrow * CPATH);
        const bfx8 xb2 = *(const bfx8*)(Wp + (size_t)kk2 * 1024 + (16 + mrow) * CPATH);
        const bfx8 xa3 = *(const bfx8*)(Wp + (size_t)kk3 * 1024 + mrow * CPATH);
        const bfx8 xb3 = *(const bfx8*)(Wp + (size_t)kk3 * 1024 + (16 + mrow) * CPATH);
        const fx4 d00 = __builtin_amdgcn_mfma_f32_16x16x32_bf16(xa0, y0, z4, 0, 0, 0);
        const fx4 d01 = __builtin_amdgcn_mfma_f32_16x16x32_bf16(xb0, y0, z4, 0, 0, 0);
        const fx4 d10 = __builtin_amdgcn_mfma_f32_16x16x32_bf16(xa1, y1, z4, 0, 0, 0);
        const fx4 d11 = __builtin_amdgcn_mfma_f32_16x16x32_bf16(xb1, y1, z4, 0, 0, 0);
        const fx4 d20 = __builtin_amdgcn_mfma_f32_16x16x32_bf16(xa2, y2, z4, 0, 0, 0);
        const fx4 d21 = __builtin_amdgcn_mfma_f32_16x16x32_bf16(xb2, y2, z4, 0, 0, 0);
        const fx4 d30 = __builtin_amdgcn_mfma_f32_16x16x32_bf16(xa3, y3, z4, 0, 0, 0);
        const fx4 d31 = __builtin_amdgcn_mfma_f32_16x16x32_bf16(xb3, y3, z4, 0, 0, 0);
#pragma unroll
        for (int r = 0; r < 4; r++) {
            atomicAdd(&accI[jj0][kq * 4 + r],      (int)rintf(d00[r] * SCALE_F));
            atomicAdd(&accI[jj0][16 + kq * 4 + r], (int)rintf(d01[r] * SCALE_F));
            atomicAdd(&accI[jj1][kq * 4 + r],      (int)rintf(d10[r] * SCALE_F));
            atomicAdd(&accI[jj1][16 + kq * 4 + r], (int)rintf(d11[r] * SCALE_F));
            atomicAdd(&accI[jj2][kq * 4 + r],      (int)rintf(d20[r] * SCALE_F));
            atomicAdd(&accI[jj2][16 + kq * 4 + r], (int)rintf(d21[r] * SCALE_F));
            atomicAdd(&accI[jj3][kq * 4 + r],      (int)rintf(d30[r] * SCALE_F));
            atomicAdd(&accI[jj3][16 + kq * 4 + r], (int)rintf(d31[r] * SCALE_F));
        }
    }
    __syncthreads();

    // Phase C: int -> f32, BN partials, packed bf16x2 writeback.
    {
        const int c0 = (tid & 15) * 2;
        const int rg = tid >> 4;          // 0..31
        float s0 = 0.f, q0 = 0.f, s1 = 0.f, q1 = 0.f;
        for (int m = 0; m < 16; m++) {
            const int r = rg + 32 * m;
            const float f0 = (float)accI[r][c0] * INV_SCALE;
            const float f1 = (float)accI[r][c0 + 1] * INV_SCALE;
            s0 += f0; q0 = fmaf(f0, f0, q0);
            s1 += f1; q1 = fmaf(f1, f1, q1);
            const unsigned pk2 = (unsigned)f2bf(f0) | ((unsigned)f2bf(f1) << 16);
            *(unsigned*)(Cbh + (size_t)(j0 + r) * CIN + p * CPATH + c0) = pk2;
        }
        redS[rg][c0] = s0; redS[rg][c0 + 1] = s1;
        redQ[rg][c0] = q0; redQ[rg][c0 + 1] = q1;
    }
    __syncthreads();
    // per-block channel totals -> global int64 fixed-point atomics
    if (tid < 32) {
        float s = 0.f;
#pragma unroll
        for (int g = 0; g < 32; g++) s += redS[g][tid];
        atomicAdd(&gstat[p * 32 + tid],
                  (ull)(long long)llrintf(s * SCALE_F));
    } else if (tid < 64) {
        const int c = tid - 32;
        float q = 0.f;
#pragma unroll
        for (int g = 0; g < 32; g++) q += redQ[g][c];
        atomicAdd(&gstat[128 + p * 32 + c],
                  (ull)(long long)llrintf(q * SCALE_F));
    }
}

// ---------------------------------------------------------------------------
// fin_mfma: out = relu(norm(Cbh)) @ finW + finb + feats.
// Each block recomputes the 128 BN scale/shift values from the global int64
// counters into LDS (256 loads + 128 rsqrt; negligible vs 80MB of traffic).
// ---------------------------------------------------------------------------
__global__ void __launch_bounds__(256, 4)
fin_mfma(const unsigned short* __restrict__ Cbh,
         const ull* __restrict__ gstat,
         const float* __restrict__ gamma,
         const float* __restrict__ beta,
         const unsigned short* __restrict__ Wft,
         const float* __restrict__ finb,
         const float* __restrict__ feats,
         float* __restrict__ out) {
    __shared__ float ssl[256];
    const int tid = threadIdx.x;
    const int w = tid >> 6, lane = tid & 63;
    const int mrow = lane & 15, kq = lane >> 4;
    const int row = blockIdx.x * 64 + w * 16 + mrow;

    if (tid < 128) {
        const float s = (float)(long long)gstat[tid] * INV_SCALE;
        const float q = (float)(long long)gstat[128 + tid] * INV_SCALE;
        const float mean = s * (1.f / NN);
        const float var = q * (1.f / NN) - mean * mean;
        const float sc = gamma[tid] * rsqrtf(var + 1e-5f);
        ssl[tid] = sc;
        ssl[128 + tid] = beta[tid] - mean * sc;
    }
    __syncthreads();

    fx4 acc[8];
#pragma unroll
    for (int g = 0; g < 8; g++) acc[g] = (fx4){0.f, 0.f, 0.f, 0.f};

#pragma unroll
    for (int kt = 0; kt < 4; ++kt) {
        const int k0 = kt * 32 + kq * 8;
        union { unsigned short s[8]; bfx8 v; } cb;
        cb.v = *(const bfx8*)(Cbh + (size_t)row * CIN + k0);
        float4 a, b;
        a.x = fmaxf(fmaf(bf2f(cb.s[0]), ssl[k0 + 0], ssl[128 + k0 + 0]), 0.f);
        a.y = fmaxf(fmaf(bf2f(cb.s[1]), ssl[k0 + 1], ssl[128 + k0 + 1]), 0.f);
        a.z = fmaxf(fmaf(bf2f(cb.s[2]), ssl[k0 + 2], ssl[128 + k0 + 2]), 0.f);
        a.w = fmaxf(fmaf(bf2f(cb.s[3]), ssl[k0 + 3], ssl[128 + k0 + 3]), 0.f);
        b.x = fmaxf(fmaf(bf2f(cb.s[4]), ssl[k0 + 4], ssl[128 + k0 + 4]), 0.f);
        b.y = fmaxf(fmaf(bf2f(cb.s[5]), ssl[k0 + 5], ssl[128 + k0 + 5]), 0.f);
        b.z = fmaxf(fmaf(bf2f(cb.s[6]), ssl[k0 + 6], ssl[128 + k0 + 6]), 0.f);
        b.w = fmaxf(fmaf(bf2f(cb.s[7]), ssl[k0 + 7], ssl[128 + k0 + 7]), 0.f);
        const bfx8 yf = pack_bf8(a, b);
#pragma unroll
        for (int g = 0; g < 8; g++) {
            const bfx8 xf = *(const bfx8*)(Wft + (size_t)(g * 16 + mrow) * CIN + kt * 32 + kq * 8);
            acc[g] = __builtin_amdgcn_mfma_f32_16x16x32_bf16(xf, yf, acc[g], 0, 0, 0);
        }
    }
#pragma unroll
    for (int g = 0; g < 8; g++) {
        const int c0 = g * 16 + kq * 4;
        const float4 fb = *(const float4*)(finb + c0);
        const float4 rs = *(const float4*)(feats + (size_t)row * CIN + c0);
        float4 o;
        o.x = acc[g][0] + fb.x + rs.x;
        o.y = acc[g][1] + fb.y + rs.y;
        o.z = acc[g][2] + fb.z + rs.z;
        o.w = acc[g][3] + fb.w + rs.w;
        *(float4*)(out + (size_t)row * CIN + c0) = o;
    }
}

// ---------------------------------------------------------------------------
extern "C" void kernel_launch(void* const* d_in, const int* in_sizes, int n_in,
                              void* d_out, int out_size, void* d_ws,
                              size_t ws_size, hipStream_t stream) {
    (void)in_sizes; (void)n_in; (void)out_size; (void)ws_size;
    const float* feats = (const float*)d_in[0];
    const float* linW  = (const float*)d_in[1];
    const float* linb  = (const float*)d_in[2];
    const float* convW = (const float*)d_in[3];
    const float* gamma = (const float*)d_in[4];
    const float* beta  = (const float*)d_in[5];
    const float* finW  = (const float*)d_in[6];
    const float* finb  = (const float*)d_in[7];
    const int*   im    = (const int*)d_in[8];
    const int*   om    = (const int*)d_in[9];
    float* out = (float*)d_out;

    char* ws = (char*)d_ws;
    unsigned short* Hb  = (unsigned short*)(ws);            // 16,781,312 (incl sentinel row + pad)
    unsigned short* Cbh = (unsigned short*)(ws + 16781312); // 16,777,216
    unsigned short* Wt  = (unsigned short*)(ws + 33558528); //    221,184
    unsigned short* Wlt = (unsigned short*)(ws + 33779712); //     32,768
    unsigned short* Wft = (unsigned short*)(ws + 33812480); //     32,768
    int*   rngAll       = (int*)(ws + 33845248);            //     55,728 -> pad 57,344
    ull*   gstat        = (ull*)(ws + 33902592);            //      2,048

    const int rng_total = NPATH * NK * (NTILE + 1);         // 13,932
    const int rng_blocks = (rng_total + 255) / 256;         // 55
    wprep_rng<<<116 + rng_blocks, 256, 0, stream>>>(convW, linW, finW, om,
                                                    Wt, Wlt, Wft, Hb, rngAll, gstat);
    lin_mfma<<<1024, 256, 0, stream>>>(feats, Wlt, linb, Hb);
    sconv15<<<dim3(NTILE, NPATH), 512, 0, stream>>>(Hb, Wt, im, om, rngAll, Cbh, gstat);
    fin_mfma<<<1024, 256, 0, stream>>>(Cbh, gstat, gamma, beta, Wft, finb, feats, out);
}

// Round 19
// 88.276 us; speedup vs baseline: 3.7100x; 1.0046x over previous
//
#include <hip/hip_runtime.h>

// ResNeXt sparse-voxel block, MI355X. Round 19 = r18 + sconv micro-cleanup:
// the dense center tap writes EVERY accI cell exactly once, so (a) the LDS
// zero-init loop is deleted (dump row is write-only garbage), and (b) the
// center phase uses plain LDS stores instead of atomics, with a
// __syncthreads() ordering center stores before the scattered-phase atomics.
// Everything else identical to r18 (88.7 us, 4 dispatches).

#define NN    65536
#define CIN   128
#define CPATH 32
#define NPATH 4
#define NK    27
#define TJ    512
#define NTILE (NN / TJ)    // 128
#define MAXG  288
#define SCALE_F 2097152.0f          // 2^21
#define INV_SCALE 4.76837158203125e-7f

typedef __attribute__((ext_vector_type(8))) short bfx8;
typedef __attribute__((ext_vector_type(4))) float fx4;
typedef unsigned long long ull;

__device__ __forceinline__ unsigned short f2bf(float f) {
    unsigned u = __builtin_bit_cast(unsigned, f);
    u += 0x7FFFu + ((u >> 16) & 1u);
    return (unsigned short)(u >> 16);
}
__device__ __forceinline__ float bf2f(unsigned short s) {
    return __builtin_bit_cast(float, (unsigned)s << 16);
}
__device__ __forceinline__ bfx8 pack_bf8(const float4 a, const float4 b) {
    union { unsigned short s[8]; bfx8 v; } u;
    u.s[0] = f2bf(a.x); u.s[1] = f2bf(a.y); u.s[2] = f2bf(a.z); u.s[3] = f2bf(a.w);
    u.s[4] = f2bf(b.x); u.s[5] = f2bf(b.y); u.s[6] = f2bf(b.z); u.s[7] = f2bf(b.w);
    return u.v;
}

// ---------------------------------------------------------------------------
// wprep_rng: b<108: convW -> Wt bf16 (+ zero Hb sentinel row);
// b in [108,112): linW -> Wlt (b==108 also zeros the 256 int64 stat counters);
// b in [112,116): finW -> Wft; b >= 116: rngAll searchsorted.
// ---------------------------------------------------------------------------
__global__ void wprep_rng(const float* __restrict__ convW,
                          const float* __restrict__ linW,
                          const float* __restrict__ finW,
                          const int* __restrict__ om,
                          unsigned short* __restrict__ Wt,
                          unsigned short* __restrict__ Wlt,
                          unsigned short* __restrict__ Wft,
                          unsigned short* __restrict__ Hb,
                          int* __restrict__ rngAll,
                          ull* __restrict__ gstat) {
    const int b = blockIdx.x;
    const int t = threadIdx.x;
    if (b < 108) {
        if (b == 0 && t < 64)
            ((unsigned*)(Hb + (size_t)NN * CIN))[t] = 0u;
        const int m = t >> 3;
        const int c0 = (t & 7) * 4;
        const float4 w = *(const float4*)(convW + ((size_t)b * CPATH + m) * CPATH + c0);
        unsigned short* o = Wt + (size_t)b * CPATH * CPATH;
        o[(c0 + 0) * CPATH + m] = f2bf(w.x);
        o[(c0 + 1) * CPATH + m] = f2bf(w.y);
        o[(c0 + 2) * CPATH + m] = f2bf(w.z);
        o[(c0 + 3) * CPATH + m] = f2bf(w.w);
    } else if (b < 112) {
        if (b == 108) gstat[t] = 0ull;    // zero 256 stat counters each call
        const int col = (b - 108) * 32 + (t >> 3);
        const int p = col >> 5, c = col & 31;
        const int k0 = (t & 7) * 16;
        for (int k = k0; k < k0 + 16; k++)
            Wlt[col * CIN + k] = f2bf(linW[(size_t)p * CIN * CPATH + k * CPATH + c]);
    } else if (b < 116) {
        const int col = (b - 112) * 32 + (t >> 3);
        const int k0 = (t & 7) * 16;
        for (int k = k0; k < k0 + 16; k++)
            Wft[col * CIN + k] = f2bf(finW[(size_t)k * CIN + col]);
    } else {
        const int idx = (b - 116) * 256 + t;     // pk*(NTILE+1) + tile
        if (idx < NPATH * NK * (NTILE + 1)) {
            const int tile = idx % (NTILE + 1);
            const int pk = idx / (NTILE + 1);
            const int bound = tile * TJ;
            const int* o = om + (size_t)pk * NN;
            int lo = 0, hi = NN;
            while (lo < hi) {
                const int mid = (lo + hi) >> 1;
                if (o[mid] < bound) lo = mid + 1; else hi = mid;
            }
            rngAll[idx] = lo;
        }
    }
}

// ---------------------------------------------------------------------------
// lin_mfma: Hb[row][c] = bf16(feats[row] @ Wcat[:,c] + linb[c]).
// ---------------------------------------------------------------------------
__global__ void __launch_bounds__(256, 4)
lin_mfma(const float* __restrict__ feats,
         const unsigned short* __restrict__ Wlt,
         const float* __restrict__ linb,
         unsigned short* __restrict__ Hb) {
    const int tid = threadIdx.x;
    const int w = tid >> 6, lane = tid & 63;
    const int mrow = lane & 15, kq = lane >> 4;
    const int row = blockIdx.x * 64 + w * 16 + mrow;

    fx4 acc[8];
#pragma unroll
    for (int g = 0; g < 8; g++) acc[g] = (fx4){0.f, 0.f, 0.f, 0.f};

#pragma unroll
    for (int kt = 0; kt < 4; ++kt) {
        const float4 y0 = *(const float4*)(feats + (size_t)row * CIN + kt * 32 + kq * 8);
        const float4 y1 = *(const float4*)(feats + (size_t)row * CIN + kt * 32 + kq * 8 + 4);
        const bfx8 yf = pack_bf8(y0, y1);
#pragma unroll
        for (int g = 0; g < 8; g++) {
            const bfx8 xf = *(const bfx8*)(Wlt + (size_t)(g * 16 + mrow) * CIN + kt * 32 + kq * 8);
            acc[g] = __builtin_amdgcn_mfma_f32_16x16x32_bf16(xf, yf, acc[g], 0, 0, 0);
        }
    }
#pragma unroll
    for (int g = 0; g < 8; g++) {
        const int c0 = g * 16 + kq * 4;
        const float4 bb = *(const float4*)(linb + c0);
        union { unsigned short s[4]; ushort4 v; } u;
        u.s[0] = f2bf(acc[g][0] + bb.x);
        u.s[1] = f2bf(acc[g][1] + bb.y);
        u.s[2] = f2bf(acc[g][2] + bb.z);
        u.s[3] = f2bf(acc[g][3] + bb.w);
        *(ushort4*)(Hb + (size_t)row * CIN + c0) = u.v;
    }
}

// ---------------------------------------------------------------------------
// sconv16: dense center tap (writes every accI cell once -> plain stores, no
// zero-init) + compacted scattered taps (int32 LDS atomics); per-channel BN
// stats -> global int64 fixed-point atomics.
// ---------------------------------------------------------------------------
__global__ void __launch_bounds__(512)
sconv16(const unsigned short* __restrict__ Hb,
        const unsigned short* __restrict__ Wt,
        const int* __restrict__ im,
        const int* __restrict__ om,
        const int* __restrict__ rngAll,
        unsigned short* __restrict__ Cbh,
        ull* __restrict__ gstat) {
    __shared__ int accI[TJ + 1][33];      // +1 dump row; stride 33 = bank-safe
    __shared__ int rng[NK][2];
    __shared__ int gkA[MAXG], gtA[MAXG];
    __shared__ int gbase[NK];
    __shared__ int Gs;
    __shared__ float redS[32][32], redQ[32][32];

    const int p = blockIdx.y;
    const int T = blockIdx.x;
    const int j0 = T * TJ;
    const int tid = threadIdx.x;
    const int lane = tid & 63;
    const int w = tid >> 6;
    const int mrow = lane & 15, kq = lane >> 4;

    if (tid < NK * 2) {
        const int k = tid >> 1, which = tid & 1;
        rng[k][which] = rngAll[((size_t)p * NK + k) * (NTILE + 1) + T + which];
    }
    __syncthreads();
    if (tid == 0) {
        int sum = 0;
#pragma unroll
        for (int k = 0; k < NK; k++) {
            gbase[k] = sum;
            if (k != 13)                      // center handled densely
                sum += (rng[k][1] - rng[k][0] + 15) >> 4;
        }
        Gs = sum;
    }
    __syncthreads();
    if (tid < NK && tid != 13) {
        const int k = tid;
        const int s = rng[k][0];
        const int n = (rng[k][1] - s + 15) >> 4;
        const int b = gbase[k];
        for (int g = 0; g < n; g++) {
            gkA[b + g] = k;
            gtA[b + g] = s + g * 16;
        }
    }

    const int G_pre = Gs;   // read after next barrier; kept for clarity
    const unsigned short* Wp = Wt + (size_t)p * NK * 1024 + kq * 8;
    const unsigned short* Hp = Hb + (size_t)p * CPATH + kq * 8;
    const int* omP = om + (size_t)p * NK * NN;
    const int* imP = im + (size_t)p * NK * NN;
    const fx4 z4 = {0.f, 0.f, 0.f, 0.f};

    // ---- dense center phase: covers every (row, channel) exactly once ----
    // Plain stores (no atomics, no zero-init needed).
    {
        const bfx8 xc0 = *(const bfx8*)(Wp + (size_t)13 * 1024 + mrow * CPATH);
        const bfx8 xc1 = *(const bfx8*)(Wp + (size_t)13 * 1024 + (16 + mrow) * CPATH);
        const int r0 = w * 64 + mrow;
        const bfx8 yc0 = *(const bfx8*)(Hp + (size_t)(j0 + r0     ) * CIN);
        const bfx8 yc1 = *(const bfx8*)(Hp + (size_t)(j0 + r0 + 16) * CIN);
        const bfx8 yc2 = *(const bfx8*)(Hp + (size_t)(j0 + r0 + 32) * CIN);
        const bfx8 yc3 = *(const bfx8*)(Hp + (size_t)(j0 + r0 + 48) * CIN);
        const fx4 e00 = __builtin_amdgcn_mfma_f32_16x16x32_bf16(xc0, yc0, z4, 0, 0, 0);
        const fx4 e01 = __builtin_amdgcn_mfma_f32_16x16x32_bf16(xc1, yc0, z4, 0, 0, 0);
        const fx4 e10 = __builtin_amdgcn_mfma_f32_16x16x32_bf16(xc0, yc1, z4, 0, 0, 0);
        const fx4 e11 = __builtin_amdgcn_mfma_f32_16x16x32_bf16(xc1, yc1, z4, 0, 0, 0);
        const fx4 e20 = __builtin_amdgcn_mfma_f32_16x16x32_bf16(xc0, yc2, z4, 0, 0, 0);
        const fx4 e21 = __builtin_amdgcn_mfma_f32_16x16x32_bf16(xc1, yc2, z4, 0, 0, 0);
        const fx4 e30 = __builtin_amdgcn_mfma_f32_16x16x32_bf16(xc0, yc3, z4, 0, 0, 0);
        const fx4 e31 = __builtin_amdgcn_mfma_f32_16x16x32_bf16(xc1, yc3, z4, 0, 0, 0);
#pragma unroll
        for (int r = 0; r < 4; r++) {
            accI[r0     ][kq * 4 + r]      = (int)rintf(e00[r] * SCALE_F);
            accI[r0     ][16 + kq * 4 + r] = (int)rintf(e01[r] * SCALE_F);
            accI[r0 + 16][kq * 4 + r]      = (int)rintf(e10[r] * SCALE_F);
            accI[r0 + 16][16 + kq * 4 + r] = (int)rintf(e11[r] * SCALE_F);
            accI[r0 + 32][kq * 4 + r]      = (int)rintf(e20[r] * SCALE_F);
            accI[r0 + 32][16 + kq * 4 + r] = (int)rintf(e21[r] * SCALE_F);
            accI[r0 + 48][kq * 4 + r]      = (int)rintf(e30[r] * SCALE_F);
            accI[r0 + 48][16 + kq * 4 + r] = (int)rintf(e31[r] * SCALE_F);
        }
    }
    __syncthreads();   // center stores ordered before scattered atomics

    // ---- scattered phase: 26 off-center taps ----
    const int G = G_pre;
    for (int base = 4 * w; base < G; base += 32) {
        int kk0 = 0, kk1 = 0, kk2 = 0, kk3 = 0;
        int tt0 = NN + mrow, tt1 = NN + mrow, tt2 = NN + mrow, tt3 = NN + mrow;
        kk0 = gkA[base]; tt0 = gtA[base] + mrow;
        if (base + 1 < G) { kk1 = gkA[base + 1]; tt1 = gtA[base + 1] + mrow; }
        if (base + 2 < G) { kk2 = gkA[base + 2]; tt2 = gtA[base + 2] + mrow; }
        if (base + 3 < G) { kk3 = gkA[base + 3]; tt3 = gtA[base + 3] + mrow; }
        const bool v0 = tt0 < rng[kk0][1], v1 = tt1 < rng[kk1][1];
        const bool v2 = tt2 < rng[kk2][1], v3 = tt3 < rng[kk3][1];
        const int jj0 = v0 ? (omP[(size_t)kk0 * NN + tt0] - j0) : TJ;
        const int ii0 = v0 ? imP[(size_t)kk0 * NN + tt0] : NN;
        const int jj1 = v1 ? (omP[(size_t)kk1 * NN + tt1] - j0) : TJ;
        const int ii1 = v1 ? imP[(size_t)kk1 * NN + tt1] : NN;
        const int jj2 = v2 ? (omP[(size_t)kk2 * NN + tt2] - j0) : TJ;
        const int ii2 = v2 ? imP[(size_t)kk2 * NN + tt2] : NN;
        const int jj3 = v3 ? (omP[(size_t)kk3 * NN + tt3] - j0) : TJ;
        const int ii3 = v3 ? imP[(size_t)kk3 * NN + tt3] : NN;
        const bfx8 y0 = *(const bfx8*)(Hp + (size_t)ii0 * CIN);
        const bfx8 y1 = *(const bfx8*)(Hp + (size_t)ii1 * CIN);
        const bfx8 y2 = *(const bfx8*)(Hp + (size_t)ii2 * CIN);
        const bfx8 y3 = *(const bfx8*)(Hp + (size_t)ii3 * CIN);
        const bfx8 xa0 = *(const bfx8*)(Wp + (size_t)kk0 * 1024 + mrow * CPATH);
        const bfx8 xb0 = *(const bfx8*)(Wp + (size_t)kk0 * 1024 + (16 + mrow) * CPATH);
        const bfx8 xa1 = *(const bfx8*)(Wp + (size_t)kk1 * 1024 + mrow * CPATH);
        const bfx8 xb1 = *(const bfx8*)(Wp + (size_t)kk1 * 1024 + (16 + mrow) * CPATH);
        const bfx8 xa2 = *(const bfx8*)(Wp + (size_t)kk2 * 1024 + mrow * CPATH);
        const bfx8 xb2 = *(const bfx8*)(Wp + (size_t)kk2 * 1024 + (16 + mrow) * CPATH);
        const bfx8 xa3 = *(const bfx8*)(Wp + (size_t)kk3 * 1024 + mrow * CPATH);
        const bfx8 xb3 = *(const bfx8*)(Wp + (size_t)kk3 * 1024 + (16 + mrow) * CPATH);
        const fx4 d00 = __builtin_amdgcn_mfma_f32_16x16x32_bf16(xa0, y0, z4, 0, 0, 0);
        const fx4 d01 = __builtin_amdgcn_mfma_f32_16x16x32_bf16(xb0, y0, z4, 0, 0, 0);
        const fx4 d10 = __builtin_amdgcn_mfma_f32_16x16x32_bf16(xa1, y1, z4, 0, 0, 0);
        const fx4 d11 = __builtin_amdgcn_mfma_f32_16x16x32_bf16(xb1, y1, z4, 0, 0, 0);
        const fx4 d20 = __builtin_amdgcn_mfma_f32_16x16x32_bf16(xa2, y2, z4, 0, 0, 0);
        const fx4 d21 = __builtin_amdgcn_mfma_f32_16x16x32_bf16(xb2, y2, z4, 0, 0, 0);
        const fx4 d30 = __builtin_amdgcn_mfma_f32_16x16x32_bf16(xa3, y3, z4, 0, 0, 0);
        const fx4 d31 = __builtin_amdgcn_mfma_f32_16x16x32_bf16(xb3, y3, z4, 0, 0, 0);
#pragma unroll
        for (int r = 0; r < 4; r++) {
            atomicAdd(&accI[jj0][kq * 4 + r],      (int)rintf(d00[r] * SCALE_F));
            atomicAdd(&accI[jj0][16 + kq * 4 + r], (int)rintf(d01[r] * SCALE_F));
            atomicAdd(&accI[jj1][kq * 4 + r],      (int)rintf(d10[r] * SCALE_F));
            atomicAdd(&accI[jj1][16 + kq * 4 + r], (int)rintf(d11[r] * SCALE_F));
            atomicAdd(&accI[jj2][kq * 4 + r],      (int)rintf(d20[r] * SCALE_F));
            atomicAdd(&accI[jj2][16 + kq * 4 + r], (int)rintf(d21[r] * SCALE_F));
            atomicAdd(&accI[jj3][kq * 4 + r],      (int)rintf(d30[r] * SCALE_F));
            atomicAdd(&accI[jj3][16 + kq * 4 + r], (int)rintf(d31[r] * SCALE_F));
        }
    }
    __syncthreads();

    // Phase C: int -> f32, BN partials, packed bf16x2 writeback.
    {
        const int c0 = (tid & 15) * 2;
        const int rg = tid >> 4;          // 0..31
        float s0 = 0.f, q0 = 0.f, s1 = 0.f, q1 = 0.f;
        for (int m = 0; m < 16; m++) {
            const int r = rg + 32 * m;
            const float f0 = (float)accI[r][c0] * INV_SCALE;
            const float f1 = (float)accI[r][c0 + 1] * INV_SCALE;
            s0 += f0; q0 = fmaf(f0, f0, q0);
            s1 += f1; q1 = fmaf(f1, f1, q1);
            const unsigned pk2 = (unsigned)f2bf(f0) | ((unsigned)f2bf(f1) << 16);
            *(unsigned*)(Cbh + (size_t)(j0 + r) * CIN + p * CPATH + c0) = pk2;
        }
        redS[rg][c0] = s0; redS[rg][c0 + 1] = s1;
        redQ[rg][c0] = q0; redQ[rg][c0 + 1] = q1;
    }
    __syncthreads();
    // per-block channel totals -> global int64 fixed-point atomics
    if (tid < 32) {
        float s = 0.f;
#pragma unroll
        for (int g = 0; g < 32; g++) s += redS[g][tid];
        atomicAdd(&gstat[p * 32 + tid],
                  (ull)(long long)llrintf(s * SCALE_F));
    } else if (tid < 64) {
        const int c = tid - 32;
        float q = 0.f;
#pragma unroll
        for (int g = 0; g < 32; g++) q += redQ[g][c];
        atomicAdd(&gstat[128 + p * 32 + c],
                  (ull)(long long)llrintf(q * SCALE_F));
    }
}

// ---------------------------------------------------------------------------
// fin_mfma: out = relu(norm(Cbh)) @ finW + finb + feats.
// Recomputes BN scale/shift per block from the global int64 counters.
// ---------------------------------------------------------------------------
__global__ void __launch_bounds__(256, 4)
fin_mfma(const unsigned short* __restrict__ Cbh,
         const ull* __restrict__ gstat,
         const float* __restrict__ gamma,
         const float* __restrict__ beta,
         const unsigned short* __restrict__ Wft,
         const float* __restrict__ finb,
         const float* __restrict__ feats,
         float* __restrict__ out) {
    __shared__ float ssl[256];
    const int tid = threadIdx.x;
    const int w = tid >> 6, lane = tid & 63;
    const int mrow = lane & 15, kq = lane >> 4;
    const int row = blockIdx.x * 64 + w * 16 + mrow;

    if (tid < 128) {
        const float s = (float)(long long)gstat[tid] * INV_SCALE;
        const float q = (float)(long long)gstat[128 + tid] * INV_SCALE;
        const float mean = s * (1.f / NN);
        const float var = q * (1.f / NN) - mean * mean;
        const float sc = gamma[tid] * rsqrtf(var + 1e-5f);
        ssl[tid] = sc;
        ssl[128 + tid] = beta[tid] - mean * sc;
    }
    __syncthreads();

    fx4 acc[8];
#pragma unroll
    for (int g = 0; g < 8; g++) acc[g] = (fx4){0.f, 0.f, 0.f, 0.f};

#pragma unroll
    for (int kt = 0; kt < 4; ++kt) {
        const int k0 = kt * 32 + kq * 8;
        union { unsigned short s[8]; bfx8 v; } cb;
        cb.v = *(const bfx8*)(Cbh + (size_t)row * CIN + k0);
        float4 a, b;
        a.x = fmaxf(fmaf(bf2f(cb.s[0]), ssl[k0 + 0], ssl[128 + k0 + 0]), 0.f);
        a.y = fmaxf(fmaf(bf2f(cb.s[1]), ssl[k0 + 1], ssl[128 + k0 + 1]), 0.f);
        a.z = fmaxf(fmaf(bf2f(cb.s[2]), ssl[k0 + 2], ssl[128 + k0 + 2]), 0.f);
        a.w = fmaxf(fmaf(bf2f(cb.s[3]), ssl[k0 + 3], ssl[128 + k0 + 3]), 0.f);
        b.x = fmaxf(fmaf(bf2f(cb.s[4]), ssl[k0 + 4], ssl[128 + k0 + 4]), 0.f);
        b.y = fmaxf(fmaf(bf2f(cb.s[5]), ssl[k0 + 5], ssl[128 + k0 + 5]), 0.f);
        b.z = fmaxf(fmaf(bf2f(cb.s[6]), ssl[k0 + 6], ssl[128 + k0 + 6]), 0.f);
        b.w = fmaxf(fmaf(bf2f(cb.s[7]), ssl[k0 + 7], ssl[128 + k0 + 7]), 0.f);
        const bfx8 yf = pack_bf8(a, b);
#pragma unroll
        for (int g = 0; g < 8; g++) {
            const bfx8 xf = *(const bfx8*)(Wft + (size_t)(g * 16 + mrow) * CIN + kt * 32 + kq * 8);
            acc[g] = __builtin_amdgcn_mfma_f32_16x16x32_bf16(xf, yf, acc[g], 0, 0, 0);
        }
    }
#pragma unroll
    for (int g = 0; g < 8; g++) {
        const int c0 = g * 16 + kq * 4;
        const float4 fb = *(const float4*)(finb + c0);
        const float4 rs = *(const float4*)(feats + (size_t)row * CIN + c0);
        float4 o;
        o.x = acc[g][0] + fb.x + rs.x;
        o.y = acc[g][1] + fb.y + rs.y;
        o.z = acc[g][2] + fb.z + rs.z;
        o.w = acc[g][3] + fb.w + rs.w;
        *(float4*)(out + (size_t)row * CIN + c0) = o;
    }
}

// ---------------------------------------------------------------------------
extern "C" void kernel_launch(void* const* d_in, const int* in_sizes, int n_in,
                              void* d_out, int out_size, void* d_ws,
                              size_t ws_size, hipStream_t stream) {
    (void)in_sizes; (void)n_in; (void)out_size; (void)ws_size;
    const float* feats = (const float*)d_in[0];
    const float* linW  = (const float*)d_in[1];
    const float* linb  = (const float*)d_in[2];
    const float* convW = (const float*)d_in[3];
    const float* gamma = (const float*)d_in[4];
    const float* beta  = (const float*)d_in[5];
    const float* finW  = (const float*)d_in[6];
    const float* finb  = (const float*)d_in[7];
    const int*   im    = (const int*)d_in[8];
    const int*   om    = (const int*)d_in[9];
    float* out = (float*)d_out;

    char* ws = (char*)d_ws;
    unsigned short* Hb  = (unsigned short*)(ws);            // 16,781,312 (incl sentinel row + pad)
    unsigned short* Cbh = (unsigned short*)(ws + 16781312); // 16,777,216
    unsigned short* Wt  = (unsigned short*)(ws + 33558528); //    221,184
    unsigned short* Wlt = (unsigned short*)(ws + 33779712); //     32,768
    unsigned short* Wft = (unsigned short*)(ws + 33812480); //     32,768
    int*   rngAll       = (int*)(ws + 33845248);            //     55,728 -> pad 57,344
    ull*   gstat        = (ull*)(ws + 33902592);            //      2,048

    const int rng_total = NPATH * NK * (NTILE + 1);         // 13,932
    const int rng_blocks = (rng_total + 255) / 256;         // 55
    wprep_rng<<<116 + rng_blocks, 256, 0, stream>>>(convW, linW, finW, om,
                                                    Wt, Wlt, Wft, Hb, rngAll, gstat);
    lin_mfma<<<1024, 256, 0, stream>>>(feats, Wlt, linb, Hb);
    sconv16<<<dim3(NTILE, NPATH), 512, 0, stream>>>(Hb, Wt, im, om, rngAll, Cbh, gstat);
    fin_mfma<<<1024, 256, 0, stream>>>(Cbh, gstat, gamma, beta, Wft, finb, feats, out);
}